// Round 9
// baseline (626.822 us; speedup 1.0000x reference)
//
#include <hip/hip_runtime.h>
#include <hip/hip_bf16.h>

// ---------------- workspace layout (float offsets, fixed small region) ----------------
#define OFF_WN   0
#define OFF_BN   1024
#define OFF_WE   1088
#define OFF_BE   1600
#define OFF_WM   1664            // 3 * 128 * 64
#define OFF_BM   26240           // 3 * 64
#define OFF_WU   26432           // 3 * 128 * 64
#define OFF_BU   51008           // 3 * 64
#define OFF_WS1  51200           // 128 * 64
#define OFF_BS1  59392
#define OFF_WS2  59456
#define OFF_BS2  59520
#define OFF_WK1  59521           // 68 * 32
#define OFF_BK1  61697
#define OFF_WK2  61729           // 32 * 16
#define OFF_BK2  62241
#define OFF_WK3  62257
#define OFF_BK3  62273
#define OFF_TS   62274           // traffic stats (4)
#define OFF_GSUM 62278           // graph-embed accumulator (64)
#define OFF_FLAG 62344           // dtype flag: 1 = inputs are f32, 0 = bf16
#define OFF_BSUM 62400           // block sums for scan (<=400)
#define OFF_BOFF 62900           // block offsets for scan (<=400)
#define OFF_H    65536           // big arrays start here (see kernel_launch)

typedef __attribute__((ext_vector_type(8))) short bfrag;   // 8 bf16 (4 VGPRs)
typedef __attribute__((ext_vector_type(4))) float ffrag;   // 4 f32 acc

__device__ __forceinline__ float bf2f(unsigned short u) {
    unsigned int i = ((unsigned int)u) << 16;
    float f;
    __builtin_memcpy(&f, &i, sizeof(f));
    return f;
}
__device__ __forceinline__ float bflo(unsigned int u) {
    unsigned int i = u << 16;
    float f; __builtin_memcpy(&f, &i, sizeof(f)); return f;
}
__device__ __forceinline__ float bfhi(unsigned int u) {
    unsigned int i = u & 0xffff0000u;
    float f; __builtin_memcpy(&f, &i, sizeof(f)); return f;
}
__device__ __forceinline__ unsigned int f2bf_rne(float f) {
    unsigned int u; __builtin_memcpy(&u, &f, 4);
    return (u + 0x7fffu + ((u >> 16) & 1u)) >> 16;
}
__device__ __forceinline__ unsigned int pack2bf(float a, float b) {
    return f2bf_rne(a) | (f2bf_rne(b) << 16);
}
// hardware packed f32->bf16 (RNE), a -> low half, b -> high half
__device__ __forceinline__ unsigned int cvt_pk_bf16(float a, float b) {
    unsigned int r;
    asm("v_cvt_pk_bf16_f32 %0, %1, %2" : "=v"(r) : "v"(a), "v"(b));
    return r;
}

// ---------------- dtype sniffer (R2 evidence: takes the f32 branch) ----------------
__global__ void detect_dtype_kernel(const unsigned short* __restrict__ nf,
                                    int* __restrict__ flag) {
    int t = threadIdx.x;  // 64 threads
    float m = 0.f;
    for (int i = t; i < 1024; i += 64) {
        float v = fabsf(bf2f(nf[i]));
        if (!isnan(v)) m = fmaxf(m, v);
        else m = 1e30f;
    }
    for (int o = 32; o > 0; o >>= 1) m = fmaxf(m, __shfl_down(m, o));
    if (t == 0) flag[0] = (m > 1e6f) ? 1 : 0;
}

// ---------------- weight conversion ----------------
struct ConvArgs {
    const void* src[19];
    int off[19];
    int n[19];
};

__global__ __launch_bounds__(256) void convert_all_kernel(
        ConvArgs a, float* __restrict__ ws, const int* __restrict__ flagp) {
    int isf32 = *flagp;
    int ai = blockIdx.y;
    int i  = blockIdx.x * blockDim.x + threadIdx.x;
    if (i < a.n[ai]) {
        float v = isf32 ? ((const float*)a.src[ai])[i]
                        : bf2f(((const unsigned short*)a.src[ai])[i]);
        ws[a.off[ai] + i] = v;
    }
}

// ---------------- transposed bf16 weight prep ----------------
// WbT[l][n*64+k]  = Wm2[l][k][n]         (12288 shorts)
// W1T[l][n*64+k]  = Wm1[l][k][n]         (12288 shorts)
// WuT[l][n*128+k] = Wu[l][k][n]          (24576 shorts)
// WeT[n*32+k]     = k<8 ? We[k][n] : 0   (2048 shorts, zero-padded K)
// Ws1T[n*128+k]   = Ws1[k][n]            (8192 shorts)
__global__ __launch_bounds__(256) void wtrans_prep_kernel(
        const float* __restrict__ ws, short* __restrict__ Wb) {
    int idx = blockIdx.x * 256 + threadIdx.x;
    if (idx < 12288) {
        int l = idx >> 12, rem = idx & 4095, n = rem >> 6, k = rem & 63;
        Wb[idx] = (short)f2bf_rne(ws[OFF_WM + l * 8192 + 4096 + k * 64 + n]);
    } else if (idx < 24576) {
        int j = idx - 12288;
        int l = j >> 12, rem = j & 4095, n = rem >> 6, k = rem & 63;
        Wb[idx] = (short)f2bf_rne(ws[OFF_WM + l * 8192 + k * 64 + n]);
    } else if (idx < 49152) {
        int j = idx - 24576;
        int l = j >> 13, rem = j & 8191, n = rem >> 7, k = rem & 127;
        Wb[idx] = (short)f2bf_rne(ws[OFF_WU + l * 8192 + k * 64 + n]);
    } else if (idx < 51200) {
        int j = idx - 49152;
        int n = j >> 5, k = j & 31;
        Wb[idx] = (k < 8) ? (short)f2bf_rne(ws[OFF_WE + k * 64 + n]) : (short)0;
    } else if (idx < 59392) {
        int j = idx - 51200;
        int n = j >> 7, k = j & 127;
        Wb[idx] = (short)f2bf_rne(ws[OFF_WS1 + k * 64 + n]);
    }
}

// ---------------- node projection: h = relu(nf @ Wn + bn) ----------------
__global__ __launch_bounds__(256) void node_proj_kernel(
        const void* __restrict__ nf, const float* __restrict__ ws,
        float* __restrict__ h, int N, const int* __restrict__ flagp) {
    int idx = blockIdx.x * blockDim.x + threadIdx.x;
    if (idx >= N * 64) return;
    int isf32 = *flagp;
    int i = idx >> 6, c = idx & 63;
    const float* Wn = ws + OFF_WN;
    float acc = ws[OFF_BN + c];
    float x[16];
    if (isf32) {
        const float* row = (const float*)nf + (size_t)i * 16;
#pragma unroll
        for (int k = 0; k < 16; ++k) x[k] = row[k];
    } else {
        const unsigned short* row = (const unsigned short*)nf + (size_t)i * 16;
#pragma unroll
        for (int k = 0; k < 16; ++k) x[k] = bf2f(row[k]);
    }
#pragma unroll
    for (int k = 0; k < 16; ++k) acc = fmaf(x[k], Wn[k * 64 + c], acc);
    h[idx] = fmaxf(acc, 0.f);
}

// ---------------- CSR build ----------------
// count also records each edge's rank within its dst bucket (coalesced
// stream write) so fill needs NO atomics: pos = off[d] + rank[e].
__global__ __launch_bounds__(256) void count_kernel(
        const int* __restrict__ dst, int* __restrict__ deg,
        int* __restrict__ rank, int E, int dorank) {
    int e = blockIdx.x * blockDim.x + threadIdx.x;
    if (e < E) {
        int r = atomicAdd(&deg[dst[e]], 1);
        if (dorank) rank[e] = r;
    }
}

__global__ __launch_bounds__(256) void scan_blocks_kernel(
        const int* __restrict__ deg, int* __restrict__ incl,
        int* __restrict__ bsum, int N) {
    int tid = threadIdx.x;
    int gid = blockIdx.x * 256 + tid;
    int v = (gid < N) ? deg[gid] : 0;
    int lane = tid & 63, w = tid >> 6;
    int x = v;
#pragma unroll
    for (int o = 1; o < 64; o <<= 1) {
        int y = __shfl_up(x, o);
        if (lane >= o) x += y;
    }
    __shared__ int wsum[4];
    __shared__ int woff[4];
    if (lane == 63) wsum[w] = x;
    __syncthreads();
    if (tid == 0) {
        int a = 0;
#pragma unroll
        for (int i = 0; i < 4; ++i) { woff[i] = a; a += wsum[i]; }
    }
    __syncthreads();
    x += woff[w];
    if (gid < N) incl[gid] = x;
    if (tid == 255) bsum[blockIdx.x] = x;
}

__global__ __launch_bounds__(256) void scan_bsum_kernel(
        const int* __restrict__ bsum, int* __restrict__ boff, int nb) {
    __shared__ int sh[256];
    int tid = threadIdx.x;
    int carry = 0;
    for (int base = 0; base < nb; base += 256) {
        int v = (base + tid < nb) ? bsum[base + tid] : 0;
        sh[tid] = v;
        __syncthreads();
        for (int o = 1; o < 256; o <<= 1) {
            int t = (tid >= o) ? sh[tid - o] : 0;
            __syncthreads();
            sh[tid] += t;
            __syncthreads();
        }
        if (base + tid < nb) boff[base + tid] = carry + sh[tid] - v;
        __syncthreads();
        carry += sh[255];
        __syncthreads();
    }
}

__global__ __launch_bounds__(256) void scan_finalize_kernel(
        const int* __restrict__ deg, const int* __restrict__ incl,
        const int* __restrict__ boff, int* __restrict__ out,
        int* __restrict__ cursor, int N, int tailval) {
    int gid = blockIdx.x * 256 + threadIdx.x;
    if (gid < N) {
        int ex = boff[blockIdx.x] + incl[gid] - deg[gid];
        out[gid] = ex;
        cursor[gid] = ex;
    }
    if (gid == 0) out[N] = tailval;
}

// fill CSR. big mode: one 24-B record {src, dst, ef as 8 bf16} per slot,
// position computed WITHOUT atomics from off[d] + rank[e].
// (R16/R18 2-pass reorder fixed write-amp but lost on time twice -> dead;
// ~61 us is the scatter floor: payload size doesn't matter, RFO-transaction
// bound.)
__global__ __launch_bounds__(256) void fill_kernel(
        const int* __restrict__ src, const int* __restrict__ dst,
        const void* __restrict__ ef, int* __restrict__ cursor,
        const int* __restrict__ rank, const int* __restrict__ off,
        int* __restrict__ eid, int* __restrict__ srcs,
        float* __restrict__ rec, int E, int big,
        const int* __restrict__ flagp) {
    int e = blockIdx.x * blockDim.x + threadIdx.x;
    if (e >= E) return;
    int d = dst[e];
    if (big) {
        int pos = off[d] + rank[e];
        unsigned p01, p23, p45, p67;
        if (*flagp) {
            const float4* p = (const float4*)ef + (size_t)e * 2;
            float4 a = p[0], b = p[1];
            p01 = pack2bf(a.x, a.y); p23 = pack2bf(a.z, a.w);
            p45 = pack2bf(b.x, b.y); p67 = pack2bf(b.z, b.w);
        } else {
            uint4 r = ((const uint4*)ef)[e];
            p01 = r.x; p23 = r.y; p45 = r.z; p67 = r.w;
        }
        float* o = rec + (size_t)pos * 6;
        *(uint2*)o       = make_uint2((unsigned)src[e], (unsigned)d);
        *(uint2*)(o + 2) = make_uint2(p01, p23);
        *(uint2*)(o + 4) = make_uint2(p45, p67);
    } else {
        int pos = atomicAdd(&cursor[d], 1);
        eid[pos] = e;
        srcs[pos] = src[e];
    }
}

// spans[i] = number of 64-slot waves node i's CSR segment touches
__global__ __launch_bounds__(256) void spans_kernel(
        const int* __restrict__ off, int* __restrict__ spans, int N) {
    int i = blockIdx.x * blockDim.x + threadIdx.x;
    if (i >= N) return;
    int k0 = off[i], k1 = off[i + 1];
    spans[i] = (k1 > k0) ? (((k1 - 1) >> 6) - (k0 >> 6) + 1) : 0;
}

// ---------------- MFMA nodeA: A[n] = h[n] @ Wm1 + bm  (A stored bf16, R19) ----------------
__global__ __launch_bounds__(256) void nodeA_mfma_kernel(
        const short* __restrict__ W1T, const float* __restrict__ bm,
        const float* __restrict__ h, unsigned short* __restrict__ Ab, int N) {
    __shared__ short lds_w[64 * 72];
    __shared__ short lds_x[4][64 * 72];
    const int tid = threadIdx.x, wid = tid >> 6, lane = tid & 63;
    const int r = lane & 15, q = lane >> 4;
    const int nb0 = blockIdx.x * 256 + wid * 64;

#pragma unroll
    for (int j = 0; j < 2; ++j) {
        int f8 = (tid * 2 + j) * 8;
        int row = f8 >> 6, k = f8 & 63;
        *(uint4*)&lds_w[row * 72 + k] = ((const uint4*)W1T)[tid * 2 + j];
    }
    short* xt = &lds_x[wid][0];
#pragma unroll 1
    for (int it = 0; it < 16; ++it) {
        int f4 = it * 64 + lane;
        int node = f4 >> 4, c4 = f4 & 15;
        int gn = nb0 + node; if (gn >= N) gn = N - 1;
        float4 v = ((const float4*)h)[(size_t)gn * 16 + c4];
        *(uint2*)&xt[node * 72 + c4 * 4] =
            make_uint2(pack2bf(v.x, v.y), pack2bf(v.z, v.w));
    }
    __syncthreads();

    bfrag bg[4][2];
#pragma unroll
    for (int ni = 0; ni < 4; ++ni)
#pragma unroll
        for (int ki = 0; ki < 2; ++ki)
            bg[ni][ki] = *(const bfrag*)&lds_w[(ni * 16 + r) * 72 + ki * 32 + q * 8];
    float buv[4];
#pragma unroll
    for (int ni = 0; ni < 4; ++ni) buv[ni] = bm[ni * 16 + r];

    ffrag C[4][4];
#pragma unroll
    for (int mi = 0; mi < 4; ++mi) {
        bfrag af[2];
#pragma unroll
        for (int ki = 0; ki < 2; ++ki)
            af[ki] = *(const bfrag*)&xt[(mi * 16 + r) * 72 + ki * 32 + q * 8];
#pragma unroll
        for (int ni = 0; ni < 4; ++ni) {
            ffrag c = {buv[ni], buv[ni], buv[ni], buv[ni]};
            c = __builtin_amdgcn_mfma_f32_16x16x32_bf16(af[0], bg[ni][0], c, 0, 0, 0);
            c = __builtin_amdgcn_mfma_f32_16x16x32_bf16(af[1], bg[ni][1], c, 0, 0, 0);
            C[mi][ni] = c;
        }
    }
#pragma unroll
    for (int mi = 0; mi < 4; ++mi)
#pragma unroll
        for (int rr = 0; rr < 4; ++rr) {
            int gn = nb0 + mi * 16 + q * 4 + rr;
            if (gn < N) {
#pragma unroll
                for (int ni = 0; ni < 4; ++ni)
                    Ab[(size_t)gn * 64 + ni * 16 + r] =
                        (unsigned short)f2bf_rne(C[mi][ni][rr]);
            }
        }
}

// ---------------- MFMA message (two-stage) + in-wave segmented reduction ----------------
// R12 structure (verified) + R17 shuffle-srow + R19 bf16 A gather.
__global__ __launch_bounds__(256, 4) void msg_mfma_red(
        const short* __restrict__ WeT, const float* __restrict__ be,
        const short* __restrict__ WbT, const float* __restrict__ rec,
        const unsigned short* __restrict__ Ab, float* __restrict__ pbuf,
        const int* __restrict__ off, const int* __restrict__ pstart, int E) {
    __shared__ short lds_ev[4][64 * 72];
    const int tid = threadIdx.x;
    const int wid = tid >> 6, lane = tid & 63;
    const int w = blockIdx.x * 4 + wid;
    if (w * 64 >= E) return;                 // wave fully out of range
    const int slot = w * 64 + lane;
    const int slotc = (slot < E) ? slot : (E - 1);

    // 24-B record: {src, dst, ef[8] bf16}
    const float* rbase = rec + (size_t)slotc * 6;
    uint2 u0 = *(const uint2*)rbase;         // src, dst
    uint2 u1 = *(const uint2*)(rbase + 2);   // ef01, ef23
    uint2 u2 = *(const uint2*)(rbase + 4);   // ef45, ef67
    int s  = (int)u0.x;
    int di = (int)u0.y;
    int pstv = pstart[di];
    int offv = off[di];

    const int r = lane & 15, q = lane >> 4;

    // per-(mi,rr) source rows via in-wave shuffle; issue ni=0 gather NOW
    int srow[16];
#pragma unroll
    for (int k = 0; k < 16; ++k)
        srow[k] = __shfl(s, (k >> 2) * 16 + q * 4 + (k & 3));   // k = mi*4+rr
    unsigned short cur[16];
#pragma unroll
    for (int k = 0; k < 16; ++k)
        cur[k] = Ab[(size_t)srow[k] * 64 + r];

    short* evb = &lds_ev[wid][0];
    short* evrow = evb + lane * 72;
    *(uint4*)(evrow) = make_uint4(u1.x, u1.y, u2.x, u2.y);
    uint4 z4 = make_uint4(0u, 0u, 0u, 0u);
    *(uint4*)(evrow + 8)  = z4;              // K-pad cols 8..31 = 0
    *(uint4*)(evrow + 16) = z4;
    *(uint4*)(evrow + 24) = z4;

    // ---- stage 1: EV^T = We^T @ EF^T + be (per-block), relu, pack to [edge][ch] ----
    bfrag afe[4];
#pragma unroll
    for (int mi = 0; mi < 4; ++mi)
        afe[mi] = *(const bfrag*)(evb + (mi * 16 + r) * 72 + q * 8);

#pragma unroll
    for (int ni = 0; ni < 4; ++ni) {
        bfrag bge = *(const bfrag*)(WeT + (ni * 16 + r) * 32 + q * 8);
        float4 b4 = *(const float4*)(be + ni * 16 + q * 4);
#pragma unroll
        for (int mi = 0; mi < 4; ++mi) {
            ffrag c = {b4.x, b4.y, b4.z, b4.w};
            c = __builtin_amdgcn_mfma_f32_16x16x32_bf16(bge, afe[mi], c, 0, 0, 0);
            unsigned lo = cvt_pk_bf16(fmaxf(c[0], 0.f), fmaxf(c[1], 0.f));
            unsigned hi = cvt_pk_bf16(fmaxf(c[2], 0.f), fmaxf(c[3], 0.f));
            *(uint2*)(evb + (mi * 16 + r) * 72 + ni * 16 + q * 4) =
                make_uint2(lo, hi);
        }
    }

    // ---- stage 2: M = EV @ Wm2 + A[src], relu, write transposed [ch][edge] ----
    bfrag af[4][2];
#pragma unroll
    for (int mi = 0; mi < 4; ++mi)
#pragma unroll
        for (int ki = 0; ki < 2; ++ki)
            af[mi][ki] = *(const bfrag*)(evb + (mi * 16 + r) * 72 + ki * 32 + q * 8);

#pragma unroll
    for (int ni = 0; ni < 4; ++ni) {
        unsigned short nxt[16];
        if (ni < 3) {
#pragma unroll
            for (int k = 0; k < 16; ++k)
                nxt[k] = Ab[(size_t)srow[k] * 64 + (ni + 1) * 16 + r];
        }
        bfrag bg0 = *(const bfrag*)(WbT + (ni * 16 + r) * 64 + q * 8);
        bfrag bg1 = *(const bfrag*)(WbT + (ni * 16 + r) * 64 + 32 + q * 8);
        ffrag C[4];
#pragma unroll
        for (int mi = 0; mi < 4; ++mi) {
            C[mi][0] = bf2f(cur[mi * 4 + 0]);
            C[mi][1] = bf2f(cur[mi * 4 + 1]);
            C[mi][2] = bf2f(cur[mi * 4 + 2]);
            C[mi][3] = bf2f(cur[mi * 4 + 3]);
        }
#pragma unroll
        for (int mi = 0; mi < 4; ++mi) {
            C[mi] = __builtin_amdgcn_mfma_f32_16x16x32_bf16(af[mi][0], bg0, C[mi], 0, 0, 0);
            C[mi] = __builtin_amdgcn_mfma_f32_16x16x32_bf16(af[mi][1], bg1, C[mi], 0, 0, 0);
        }
#pragma unroll
        for (int mi = 0; mi < 4; ++mi) {
            unsigned lo = cvt_pk_bf16(fmaxf(C[mi][0], 0.f), fmaxf(C[mi][1], 0.f));
            unsigned hi = cvt_pk_bf16(fmaxf(C[mi][2], 0.f), fmaxf(C[mi][3], 0.f));
            *(uint2*)(evb + (ni * 16 + r) * 72 + mi * 16 + q * 4) =
                make_uint2(lo, hi);
        }
        if (ni < 3) {
#pragma unroll
            for (int k = 0; k < 16; ++k) cur[k] = nxt[k];
        }
    }

    // ---- in-wave segmented reduction over edges (lane = channel) ----
    int kmax = E - w * 64; if (kmax > 64) kmax = 64;
    if (kmax < 64) {
        for (int k = kmax; k < 64; ++k) evb[lane * 72 + k] = 0;
    }
    int prevd = __shfl_up(di, 1);
    unsigned long long sm = __ballot(lane != 0 && di != prevd);
    int curp = __shfl(pstv, 0) + (w - (__shfl(offv, 0) >> 6));
    float acc = 0.f;
#pragma unroll
    for (int g = 0; g < 8; ++g) {
        uint4 v = *(const uint4*)(evb + lane * 72 + g * 8);
        float f0 = bflo(v.x), f1 = bfhi(v.x), f2 = bflo(v.y), f3 = bfhi(v.y);
        float f4 = bflo(v.z), f5 = bfhi(v.z), f6 = bflo(v.w), f7 = bfhi(v.w);
        unsigned gm = (unsigned)(sm >> (g * 8)) & 0xffu;
        if (gm == 0) {   // wave-uniform: no boundary in this 8-edge group
            acc += (((f0 + f1) + (f2 + f3)) + ((f4 + f5) + (f6 + f7)));
        } else {
            float fv[8] = {f0, f1, f2, f3, f4, f5, f6, f7};
#pragma unroll
            for (int j = 0; j < 8; ++j) {
                if (gm & (1u << j)) {
                    pbuf[(size_t)curp * 64 + lane] = acc;
                    acc = 0.f;
                    curp = __shfl(pstv, g * 8 + j);
                }
                acc += fv[j];
            }
        }
    }
    pbuf[(size_t)curp * 64 + lane] = acc;
}

// ---------------- MFMA update (R20: fixup fused into staging) ----------------
// h = relu([h, agg] @ Wu + bu) + h, where agg[i] is computed ON THE FLY as the
// sum of node i's pbuf partial rows (same j-ascending f32 order as the old
// fixup kernel, then the same pack2bf rounding -> bit-identical). Deletes the
// fixup kernel and the 25.6 MB/layer agg write+read round-trip.
__global__ __launch_bounds__(128) void update_mfma_kernel(
        const short* __restrict__ WuT, const float* __restrict__ bu,
        float* __restrict__ h, const float* __restrict__ agg,
        const float* __restrict__ pbuf, const int* __restrict__ off,
        const int* __restrict__ pstart, int usepbuf, int N) {
    __shared__ short lds_w[64 * 136];
    __shared__ short lds_x[2][64 * 136];
    const int tid = threadIdx.x, wid = tid >> 6, lane = tid & 63;
    const int r = lane & 15, q = lane >> 4;
    const int nb0 = blockIdx.x * 128 + wid * 64;
#pragma unroll
    for (int j = 0; j < 8; ++j) {
        int f8 = (tid * 8 + j) * 8;
        int row = f8 >> 7, k = f8 & 127;
        *(uint4*)&lds_w[row * 136 + k] = ((const uint4*)WuT)[tid * 8 + j];
    }
    short* xt = &lds_x[wid][0];
#pragma unroll 1
    for (int it = 0; it < 32; ++it) {
        int f4 = it * 64 + lane;
        int node = f4 >> 5, c4 = f4 & 31;
        int gn = nb0 + node; if (gn >= N) gn = N - 1;
        float4 v;
        if (c4 < 16) {
            v = ((const float4*)h)[(size_t)gn * 16 + c4];
        } else if (!usepbuf) {
            v = ((const float4*)agg)[(size_t)gn * 16 + (c4 - 16)];
        } else {
            int k0 = off[gn], k1 = off[gn + 1];
            v = make_float4(0.f, 0.f, 0.f, 0.f);
            if (k1 > k0) {
                int nsp = ((k1 - 1) >> 6) - (k0 >> 6) + 1;
                const float4* pr = (const float4*)pbuf
                                 + (size_t)pstart[gn] * 16 + (c4 - 16);
                for (int j = 0; j < nsp; ++j) {
                    float4 t = pr[(size_t)j * 16];
                    v.x += t.x; v.y += t.y; v.z += t.z; v.w += t.w;
                }
            }
        }
        *(uint2*)&xt[node * 136 + c4 * 4] =
            make_uint2(pack2bf(v.x, v.y), pack2bf(v.z, v.w));
    }
    __syncthreads();
    bfrag bg[4][4];
#pragma unroll
    for (int ni = 0; ni < 4; ++ni)
#pragma unroll
        for (int ki = 0; ki < 4; ++ki)
            bg[ni][ki] = *(const bfrag*)&lds_w[(ni * 16 + r) * 136 + ki * 32 + q * 8];
    float buv[4];
#pragma unroll
    for (int ni = 0; ni < 4; ++ni) buv[ni] = bu[ni * 16 + r];
    ffrag C[4][4];
#pragma unroll
    for (int mi = 0; mi < 4; ++mi) {
        bfrag af[4];
#pragma unroll
        for (int ki = 0; ki < 4; ++ki)
            af[ki] = *(const bfrag*)&xt[(mi * 16 + r) * 136 + ki * 32 + q * 8];
#pragma unroll
        for (int ni = 0; ni < 4; ++ni) {
            ffrag c = {buv[ni], buv[ni], buv[ni], buv[ni]};
#pragma unroll
            for (int ki = 0; ki < 4; ++ki)
                c = __builtin_amdgcn_mfma_f32_16x16x32_bf16(af[ki], bg[ni][ki], c, 0, 0, 0);
            C[mi][ni] = c;
        }
    }
#pragma unroll
    for (int mi = 0; mi < 4; ++mi)
#pragma unroll
        for (int rr = 0; rr < 4; ++rr) {
            int nl = mi * 16 + q * 4 + rr;
            int gn = nb0 + nl;
            if (gn < N) {
#pragma unroll
                for (int ni = 0; ni < 4; ++ni) {
                    float hold = bf2f((unsigned short)xt[nl * 136 + ni * 16 + r]);
                    h[(size_t)gn * 64 + ni * 16 + r] =
                        fmaxf(C[mi][ni][rr], 0.f) + hold;
                }
            }
        }
}

// ---------------- fallback gather (tiny ws; R3 structure; bf16 A) ----------------
__global__ __launch_bounds__(256) void gather_msg_fallback(
        const float* __restrict__ Wm2, const float* __restrict__ We,
        const float* __restrict__ be, const void* __restrict__ ef,
        const int* __restrict__ srcs, const int* __restrict__ eid,
        const int* __restrict__ off, const unsigned short* __restrict__ Ab,
        float* __restrict__ agg, int N, const int* __restrict__ flagp) {
    int i = blockIdx.x * blockDim.x + threadIdx.x;
    if (i >= N) return;
    int isf32 = *flagp;
    int k0 = off[i], k1 = off[i + 1];
    float acc[64];
#pragma unroll
    for (int c = 0; c < 64; ++c) acc[c] = 0.f;
    for (int k = k0; k < k1; ++k) {
        int s = srcs[k];
        int e = eid[k];
        const uint4* a4 = (const uint4*)(Ab + (size_t)s * 64);
        float t[64];
#pragma unroll
        for (int c = 0; c < 8; ++c) {
            uint4 v = a4[c];
            t[8 * c]     = bflo(v.x); t[8 * c + 1] = bfhi(v.x);
            t[8 * c + 2] = bflo(v.y); t[8 * c + 3] = bfhi(v.y);
            t[8 * c + 4] = bflo(v.z); t[8 * c + 5] = bfhi(v.z);
            t[8 * c + 6] = bflo(v.w); t[8 * c + 7] = bfhi(v.w);
        }
        float efv[8];
        if (isf32) {
            const float4* e4 = (const float4*)ef + (size_t)e * 2;
            float4 ra = e4[0], rb = e4[1];
            efv[0]=ra.x; efv[1]=ra.y; efv[2]=ra.z; efv[3]=ra.w;
            efv[4]=rb.x; efv[5]=rb.y; efv[6]=rb.z; efv[7]=rb.w;
        } else {
            uint4 rr = ((const uint4*)ef)[e];
            efv[0]=bflo(rr.x); efv[1]=bfhi(rr.x); efv[2]=bflo(rr.y); efv[3]=bfhi(rr.y);
            efv[4]=bflo(rr.z); efv[5]=bfhi(rr.z); efv[6]=bflo(rr.w); efv[7]=bfhi(rr.w);
        }
#pragma unroll 1
        for (int d0 = 0; d0 < 64; d0 += 8) {
            float ev[8];
#pragma unroll
            for (int dd = 0; dd < 8; ++dd) {
                float a = be[d0 + dd];
#pragma unroll
                for (int kk = 0; kk < 8; ++kk) a = fmaf(efv[kk], We[kk * 64 + d0 + dd], a);
                ev[dd] = fmaxf(a, 0.f);
            }
#pragma unroll
            for (int dd = 0; dd < 8; ++dd) {
                const float* w = Wm2 + (d0 + dd) * 64;
#pragma unroll
                for (int c = 0; c < 64; ++c) t[c] = fmaf(ev[dd], w[c], t[c]);
            }
        }
#pragma unroll
        for (int c = 0; c < 64; ++c) acc[c] += fmaxf(t[c], 0.f);
    }
    float4* o4 = (float4*)(agg + (size_t)i * 64);
#pragma unroll
    for (int c = 0; c < 16; ++c)
        o4[c] = make_float4(acc[4 * c], acc[4 * c + 1], acc[4 * c + 2], acc[4 * c + 3]);
}

// ---------------- MFMA scores: out[p] = relu([h_s|h_d]@Ws1+bs1) . Ws2 + bs2 ----------------
__global__ __launch_bounds__(128) void scores_mfma_kernel(
        const short* __restrict__ Ws1T, const float* __restrict__ bs1,
        const float* __restrict__ Ws2, const float* __restrict__ bs2,
        const int* __restrict__ ods, const int* __restrict__ odd,
        const float* __restrict__ h, void* __restrict__ out, int P,
        const int* __restrict__ flagp) {
    __shared__ short lds_w[64 * 136];
    __shared__ short lds_x[2][64 * 136];
    const int tid = threadIdx.x, wid = tid >> 6, lane = tid & 63;
    const int r = lane & 15, q = lane >> 4;
    const int pb0 = blockIdx.x * 128 + wid * 64;
#pragma unroll
    for (int j = 0; j < 8; ++j) {
        int f8 = (tid * 8 + j) * 8;
        int row = f8 >> 7, k = f8 & 127;
        *(uint4*)&lds_w[row * 136 + k] = ((const uint4*)Ws1T)[tid * 8 + j];
    }
    short* xt = &lds_x[wid][0];
#pragma unroll 1
    for (int it = 0; it < 32; ++it) {
        int f4 = it * 64 + lane;
        int pr = f4 >> 5, c4 = f4 & 31;
        int gp = pb0 + pr; if (gp >= P) gp = P - 1;
        int node = (c4 < 16) ? ods[gp] : odd[gp];
        int cc = (c4 < 16) ? c4 : (c4 - 16);
        float4 v = ((const float4*)h)[(size_t)node * 16 + cc];
        *(uint2*)&xt[pr * 136 + c4 * 4] =
            make_uint2(pack2bf(v.x, v.y), pack2bf(v.z, v.w));
    }
    __syncthreads();

    bfrag bg[4][4];
#pragma unroll
    for (int ni = 0; ni < 4; ++ni)
#pragma unroll
        for (int ki = 0; ki < 4; ++ki)
            bg[ni][ki] = *(const bfrag*)&lds_w[(ni * 16 + r) * 136 + ki * 32 + q * 8];
    float buv[4], w2v[4];
#pragma unroll
    for (int ni = 0; ni < 4; ++ni) { buv[ni] = bs1[ni * 16 + r]; w2v[ni] = Ws2[ni * 16 + r]; }
    int isf32 = *flagp;
    float b2 = bs2[0];

#pragma unroll
    for (int mi = 0; mi < 4; ++mi) {
        bfrag af[4];
#pragma unroll
        for (int ki = 0; ki < 4; ++ki)
            af[ki] = *(const bfrag*)&xt[(mi * 16 + r) * 136 + ki * 32 + q * 8];
        float part[4] = {0.f, 0.f, 0.f, 0.f};
#pragma unroll
        for (int ni = 0; ni < 4; ++ni) {
            ffrag c = {buv[ni], buv[ni], buv[ni], buv[ni]};
#pragma unroll
            for (int ki = 0; ki < 4; ++ki)
                c = __builtin_amdgcn_mfma_f32_16x16x32_bf16(af[ki], bg[ni][ki], c, 0, 0, 0);
#pragma unroll
            for (int rr = 0; rr < 4; ++rr)
                part[rr] = fmaf(fmaxf(c[rr], 0.f), w2v[ni], part[rr]);
        }
#pragma unroll
        for (int rr = 0; rr < 4; ++rr) {
            float v = part[rr];
            v += __shfl_xor(v, 1); v += __shfl_xor(v, 2);
            v += __shfl_xor(v, 4); v += __shfl_xor(v, 8);
            if (r == 0) {
                int p = pb0 + mi * 16 + q * 4 + rr;
                if (p < P) {
                    float score = v + b2;
                    if (isf32) ((float*)out)[p] = score;
                    else ((__hip_bfloat16*)out)[p] = __float2bfloat16(score);
                }
            }
        }
    }
}

// ---------------- graph embed ----------------
__global__ __launch_bounds__(256) void embed_kernel(
        const float* __restrict__ h, float* __restrict__ gsum, int N) {
    __shared__ float red[256];
    int c = threadIdx.x & 63;
    int sub = threadIdx.x >> 6;   // 0..3
    float a = 0.f;
    for (int i = blockIdx.x * 4 + sub; i < N; i += gridDim.x * 4)
        a += h[(size_t)i * 64 + c];
    red[threadIdx.x] = a;
    __syncthreads();
    if (threadIdx.x < 64) {
        float t = red[threadIdx.x] + red[threadIdx.x + 64] +
                  red[threadIdx.x + 128] + red[threadIdx.x + 192];
        unsafeAtomicAdd(&gsum[threadIdx.x], t);
    }
}

// ---------------- dynamic-K head (wave-parallel; R14 verified) ----------------
__global__ void khead_kernel(const float* __restrict__ ws,
                             void* __restrict__ out, int N, int P,
                             const int* __restrict__ flagp) {
    __shared__ float sh1[32];
    __shared__ float sh2[16];
    int lane = threadIdx.x;   // 64 threads, 1 wave
    float invN = 1.f / (float)N;
    float a1 = (lane < 32) ? ws[OFF_BK1 + lane] : 0.f;
#pragma unroll
    for (int i = 0; i < 68; ++i) {
        float xi = (i < 64) ? ws[OFF_GSUM + i] * invN : ws[OFF_TS + i - 64];
        if (lane < 32) a1 = fmaf(xi, ws[OFF_WK1 + i * 32 + lane], a1);
    }
    if (lane < 32) sh1[lane] = fmaxf(a1, 0.f);
    __syncthreads();
    float a2 = (lane < 16) ? ws[OFF_BK2 + lane] : 0.f;
#pragma unroll
    for (int j = 0; j < 32; ++j) {
        if (lane < 16) a2 = fmaf(sh1[j], ws[OFF_WK2 + j * 16 + lane], a2);
    }
    if (lane < 16) sh2[lane] = fmaxf(a2, 0.f);
    __syncthreads();
    if (lane == 0) {
        float raw = ws[OFF_BK3];
#pragma unroll
        for (int k2 = 0; k2 < 16; ++k2) raw = fmaf(sh2[k2], ws[OFF_WK3 + k2], raw);
        float sig = 1.f / (1.f + expf(-raw));
        float k = 1.f + 49.f * sig;
        if (*flagp) ((float*)out)[P] = k;
        else ((__hip_bfloat16*)out)[P] = __float2bfloat16(k);
    }
}

extern "C" void kernel_launch(void* const* d_in, const int* in_sizes, int n_in,
                              void* d_out, int out_size, void* d_ws, size_t ws_size,
                              hipStream_t stream) {
    const void* nf = d_in[0];
    const int*  ei = (const int*)d_in[1];
    const void* ef = d_in[2];
    const int*  od = (const int*)d_in[3];
    float* ws = (float*)d_ws;

    const int N = in_sizes[0] / 16;   // 50000
    const int E = in_sizes[1] / 2;    // 1200000
    const int P = in_sizes[3] / 2;    // 10000

    // layout: h, agg, A(bf16); deg/spans, off, cursor, pstart, eid, srcs, Wtrans, rank; rec; pbuf
    float* h      = ws + OFF_H;
    float* agg    = h + (size_t)N * 64;
    unsigned short* Ab = (unsigned short*)(agg + (size_t)N * 64);  // N*64 bf16 (half the f32 slot)
    int*   deg    = (int*)(agg + (size_t)N * 64 + (size_t)N * 32); // N (reused as spans)
    int*   off    = deg + N;                      // N+1
    int*   cursor = off + N + 1;                  // N
    int*   pstart = cursor + N;                   // N+1
    int*   eid    = pstart + N + 1;               // E (fallback only)
    int*   srcs   = eid + E;                      // E (fallback only)
    short* WbT    = (short*)(srcs + E);           // 59392 shorts: WbT|W1T|WuT|WeT|Ws1T
    short* W1T    = WbT + 12288;
    short* WuT    = WbT + 24576;
    short* WeT    = WbT + 49152;
    short* Ws1T   = WbT + 51200;
    int*   rank   = (int*)(WbT + 59392);          // E (big path only)
    int*   flag   = (int*)(ws + OFF_FLAG);
    int*   bsum   = (int*)(ws + OFF_BSUM);
    int*   boff   = (int*)(ws + OFF_BOFF);

    size_t fsofar = (size_t)OFF_H + 2 * (size_t)N * 64 + (size_t)N * 32
                  + (size_t)(N + (N + 1) + N + (N + 1) + E + E + E) + 29696;
    size_t recOff = (fsofar + 7) & ~(size_t)7;            // record base align
    float* rec = ws + recOff;
    size_t pbufOff = recOff + (size_t)E * 6;
    float* pbuf = ws + pbufOff;
    long pbufRows = (long)N + E / 64 + 128;
    size_t needBytes = (pbufOff + (size_t)pbufRows * 64) * sizeof(float);
    const bool big = (ws_size >= needBytes);

    const int* srcv = ei;
    const int* dstv = ei + E;

    // 0. dtype detect
    detect_dtype_kernel<<<1, 64, 0, stream>>>((const unsigned short*)nf, flag);

    // 1. convert weights to f32 in ws; build transposed bf16 weights
    ConvArgs ca;
    const int srcidx[19] = {5, 6, 7, 8, 9, 10, 11, 12, 13, 14, 15, 16, 17, 18, 19, 20, 21, 22, 4};
    const int wsoff[19]  = {OFF_WN, OFF_BN, OFF_WE, OFF_BE, OFF_WM, OFF_BM, OFF_WU, OFF_BU,
                            OFF_WS1, OFF_BS1, OFF_WS2, OFF_BS2, OFF_WK1, OFF_BK1, OFF_WK2,
                            OFF_BK2, OFF_WK3, OFF_BK3, OFF_TS};
    int maxn = 0;
    for (int i = 0; i < 19; ++i) {
        ca.src[i] = d_in[srcidx[i]];
        ca.off[i] = wsoff[i];
        ca.n[i]   = in_sizes[srcidx[i]];
        if (ca.n[i] > maxn) maxn = ca.n[i];
    }
    dim3 cgrid((maxn + 255) / 256, 19);
    convert_all_kernel<<<cgrid, 256, 0, stream>>>(ca, ws, flag);
    wtrans_prep_kernel<<<232, 256, 0, stream>>>(ws, WbT);

    // 2. node projection
    node_proj_kernel<<<(N * 64 + 255) / 256, 256, 0, stream>>>(nf, ws, h, N, flag);

    // 3. build CSR by dst (once). count records per-edge rank so fill
    //    needs no atomics in big mode.
    hipMemsetAsync(deg, 0, (size_t)N * sizeof(int), stream);
    count_kernel<<<(E + 255) / 256, 256, 0, stream>>>(dstv, deg, rank, E, big ? 1 : 0);
    int nb = (N + 255) / 256;
    scan_blocks_kernel<<<nb, 256, 0, stream>>>(deg, cursor, bsum, N);
    scan_bsum_kernel<<<1, 256, 0, stream>>>(bsum, boff, nb);
    scan_finalize_kernel<<<nb, 256, 0, stream>>>(deg, cursor, boff, off, cursor, N, E);
    fill_kernel<<<(E + 255) / 256, 256, 0, stream>>>(
        srcv, dstv, ef, cursor, rank, off, eid, srcs, rec, E, big ? 1 : 0, flag);

    // 3b. pstart = exclusive scan of wave-span counts (big path only)
    if (big) {
        spans_kernel<<<nb, 256, 0, stream>>>(off, deg, N);       // deg := spans
        scan_blocks_kernel<<<nb, 256, 0, stream>>>(deg, cursor, bsum, N);
        scan_bsum_kernel<<<1, 256, 0, stream>>>(bsum, boff, nb);
        scan_finalize_kernel<<<nb, 256, 0, stream>>>(deg, cursor, boff, pstart, cursor, N, 0);
    }

    // 4. GNN layers (R20 structure: nodeA -> msg -> fused fixup+update)
    const int mblocks = (E + 255) / 256;
    const int ablocks = (N + 255) / 256;
    const int ublocks = (N + 127) / 128;
    for (int l = 0; l < 3; ++l) {
        nodeA_mfma_kernel<<<ablocks, 256, 0, stream>>>(
            W1T + l * 4096, ws + OFF_BM + l * 64, h, Ab, N);
        if (big) {
            msg_mfma_red<<<mblocks, 256, 0, stream>>>(
                WeT, ws + OFF_BE, WbT + l * 4096, rec, Ab, pbuf, off, pstart, E);
            update_mfma_kernel<<<ublocks, 128, 0, stream>>>(
                WuT + l * 8192, ws + OFF_BU + l * 64, h, agg,
                pbuf, off, pstart, 1, N);
        } else {
            const float* Wm2 = ws + OFF_WM + l * 8192 + 4096;
            gather_msg_fallback<<<(N + 255) / 256, 256, 0, stream>>>(
                Wm2, ws + OFF_WE, ws + OFF_BE, ef, srcs, eid, off, Ab, agg, N, flag);
            update_mfma_kernel<<<ublocks, 128, 0, stream>>>(
                WuT + l * 8192, ws + OFF_BU + l * 64, h, agg,
                pbuf, off, pstart, 0, N);
        }
    }

    // 5. per-flow scores (MFMA)
    scores_mfma_kernel<<<(P + 127) / 128, 128, 0, stream>>>(
        Ws1T, ws + OFF_BS1, ws + OFF_WS2, ws + OFF_BS2,
        od, od + P, h, d_out, P, flag);

    // 6. graph embedding + dynamic-K head
    hipMemsetAsync(ws + OFF_GSUM, 0, 64 * sizeof(float), stream);
    embed_kernel<<<256, 256, 0, stream>>>(h, ws + OFF_GSUM, N);
    khead_kernel<<<1, 64, 0, stream>>>(ws, d_out, N, P, flag);
}

// Round 10
// 584.834 us; speedup vs baseline: 1.0718x; 1.0718x over previous
//
#include <hip/hip_runtime.h>
#include <hip/hip_bf16.h>

// ---------------- workspace layout (float offsets, fixed small region) ----------------
#define OFF_WN   0
#define OFF_BN   1024
#define OFF_WE   1088
#define OFF_BE   1600
#define OFF_WM   1664            // 3 * 128 * 64
#define OFF_BM   26240           // 3 * 64
#define OFF_WU   26432           // 3 * 128 * 64
#define OFF_BU   51008           // 3 * 64
#define OFF_WS1  51200           // 128 * 64
#define OFF_BS1  59392
#define OFF_WS2  59456
#define OFF_BS2  59520
#define OFF_WK1  59521           // 68 * 32
#define OFF_BK1  61697
#define OFF_WK2  61729           // 32 * 16
#define OFF_BK2  62241
#define OFF_WK3  62257
#define OFF_BK3  62273
#define OFF_TS   62274           // traffic stats (4)
#define OFF_GSUM 62278           // graph-embed accumulator (64)
#define OFF_FLAG 62344           // dtype flag: 1 = inputs are f32, 0 = bf16
#define OFF_BSUM 62400           // block sums for scan (<=400)
#define OFF_BOFF 62900           // block offsets for scan (<=400)
#define OFF_H    65536           // big arrays start here (see kernel_launch)

typedef __attribute__((ext_vector_type(8))) short bfrag;   // 8 bf16 (4 VGPRs)
typedef __attribute__((ext_vector_type(4))) float ffrag;   // 4 f32 acc

__device__ __forceinline__ float bf2f(unsigned short u) {
    unsigned int i = ((unsigned int)u) << 16;
    float f;
    __builtin_memcpy(&f, &i, sizeof(f));
    return f;
}
__device__ __forceinline__ float bflo(unsigned int u) {
    unsigned int i = u << 16;
    float f; __builtin_memcpy(&f, &i, sizeof(f)); return f;
}
__device__ __forceinline__ float bfhi(unsigned int u) {
    unsigned int i = u & 0xffff0000u;
    float f; __builtin_memcpy(&f, &i, sizeof(f)); return f;
}
__device__ __forceinline__ unsigned int f2bf_rne(float f) {
    unsigned int u; __builtin_memcpy(&u, &f, 4);
    return (u + 0x7fffu + ((u >> 16) & 1u)) >> 16;
}
__device__ __forceinline__ unsigned int pack2bf(float a, float b) {
    return f2bf_rne(a) | (f2bf_rne(b) << 16);
}
// hardware packed f32->bf16 (RNE), a -> low half, b -> high half
__device__ __forceinline__ unsigned int cvt_pk_bf16(float a, float b) {
    unsigned int r;
    asm("v_cvt_pk_bf16_f32 %0, %1, %2" : "=v"(r) : "v"(a), "v"(b));
    return r;
}

// ---------------- dtype sniffer (R2 evidence: takes the f32 branch) ----------------
__global__ void detect_dtype_kernel(const unsigned short* __restrict__ nf,
                                    int* __restrict__ flag) {
    int t = threadIdx.x;  // 64 threads
    float m = 0.f;
    for (int i = t; i < 1024; i += 64) {
        float v = fabsf(bf2f(nf[i]));
        if (!isnan(v)) m = fmaxf(m, v);
        else m = 1e30f;
    }
    for (int o = 32; o > 0; o >>= 1) m = fmaxf(m, __shfl_down(m, o));
    if (t == 0) flag[0] = (m > 1e6f) ? 1 : 0;
}

// ---------------- weight conversion ----------------
struct ConvArgs {
    const void* src[19];
    int off[19];
    int n[19];
};

__global__ __launch_bounds__(256) void convert_all_kernel(
        ConvArgs a, float* __restrict__ ws, const int* __restrict__ flagp) {
    int isf32 = *flagp;
    int ai = blockIdx.y;
    int i  = blockIdx.x * blockDim.x + threadIdx.x;
    if (i < a.n[ai]) {
        float v = isf32 ? ((const float*)a.src[ai])[i]
                        : bf2f(((const unsigned short*)a.src[ai])[i]);
        ws[a.off[ai] + i] = v;
    }
}

// ---------------- transposed bf16 weight prep ----------------
// WbT[l][n*64+k]  = Wm2[l][k][n]         (12288 shorts)
// W1T[l][n*64+k]  = Wm1[l][k][n]         (12288 shorts)
// WuT[l][n*128+k] = Wu[l][k][n]          (24576 shorts)
// WeT[n*32+k]     = k<8 ? We[k][n] : 0   (2048 shorts, zero-padded K)
// Ws1T[n*128+k]   = Ws1[k][n]            (8192 shorts)
__global__ __launch_bounds__(256) void wtrans_prep_kernel(
        const float* __restrict__ ws, short* __restrict__ Wb) {
    int idx = blockIdx.x * 256 + threadIdx.x;
    if (idx < 12288) {
        int l = idx >> 12, rem = idx & 4095, n = rem >> 6, k = rem & 63;
        Wb[idx] = (short)f2bf_rne(ws[OFF_WM + l * 8192 + 4096 + k * 64 + n]);
    } else if (idx < 24576) {
        int j = idx - 12288;
        int l = j >> 12, rem = j & 4095, n = rem >> 6, k = rem & 63;
        Wb[idx] = (short)f2bf_rne(ws[OFF_WM + l * 8192 + k * 64 + n]);
    } else if (idx < 49152) {
        int j = idx - 24576;
        int l = j >> 13, rem = j & 8191, n = rem >> 7, k = rem & 127;
        Wb[idx] = (short)f2bf_rne(ws[OFF_WU + l * 8192 + k * 64 + n]);
    } else if (idx < 51200) {
        int j = idx - 49152;
        int n = j >> 5, k = j & 31;
        Wb[idx] = (k < 8) ? (short)f2bf_rne(ws[OFF_WE + k * 64 + n]) : (short)0;
    } else if (idx < 59392) {
        int j = idx - 51200;
        int n = j >> 7, k = j & 127;
        Wb[idx] = (short)f2bf_rne(ws[OFF_WS1 + k * 64 + n]);
    }
}

// ---------------- node projection: h = relu(nf @ Wn + bn) ----------------
__global__ __launch_bounds__(256) void node_proj_kernel(
        const void* __restrict__ nf, const float* __restrict__ ws,
        float* __restrict__ h, int N, const int* __restrict__ flagp) {
    int idx = blockIdx.x * blockDim.x + threadIdx.x;
    if (idx >= N * 64) return;
    int isf32 = *flagp;
    int i = idx >> 6, c = idx & 63;
    const float* Wn = ws + OFF_WN;
    float acc = ws[OFF_BN + c];
    float x[16];
    if (isf32) {
        const float* row = (const float*)nf + (size_t)i * 16;
#pragma unroll
        for (int k = 0; k < 16; ++k) x[k] = row[k];
    } else {
        const unsigned short* row = (const unsigned short*)nf + (size_t)i * 16;
#pragma unroll
        for (int k = 0; k < 16; ++k) x[k] = bf2f(row[k]);
    }
#pragma unroll
    for (int k = 0; k < 16; ++k) acc = fmaf(x[k], Wn[k * 64 + c], acc);
    h[idx] = fmaxf(acc, 0.f);
}

// ---------------- CSR build ----------------
// count also records each edge's rank within its dst bucket (coalesced
// stream write) so fill needs NO atomics: pos = off[d] + rank[e].
__global__ __launch_bounds__(256) void count_kernel(
        const int* __restrict__ dst, int* __restrict__ deg,
        int* __restrict__ rank, int E, int dorank) {
    int e = blockIdx.x * blockDim.x + threadIdx.x;
    if (e < E) {
        int r = atomicAdd(&deg[dst[e]], 1);
        if (dorank) rank[e] = r;
    }
}

__global__ __launch_bounds__(256) void scan_blocks_kernel(
        const int* __restrict__ deg, int* __restrict__ incl,
        int* __restrict__ bsum, int N) {
    int tid = threadIdx.x;
    int gid = blockIdx.x * 256 + tid;
    int v = (gid < N) ? deg[gid] : 0;
    int lane = tid & 63, w = tid >> 6;
    int x = v;
#pragma unroll
    for (int o = 1; o < 64; o <<= 1) {
        int y = __shfl_up(x, o);
        if (lane >= o) x += y;
    }
    __shared__ int wsum[4];
    __shared__ int woff[4];
    if (lane == 63) wsum[w] = x;
    __syncthreads();
    if (tid == 0) {
        int a = 0;
#pragma unroll
        for (int i = 0; i < 4; ++i) { woff[i] = a; a += wsum[i]; }
    }
    __syncthreads();
    x += woff[w];
    if (gid < N) incl[gid] = x;
    if (tid == 255) bsum[blockIdx.x] = x;
}

__global__ __launch_bounds__(256) void scan_bsum_kernel(
        const int* __restrict__ bsum, int* __restrict__ boff, int nb) {
    __shared__ int sh[256];
    int tid = threadIdx.x;
    int carry = 0;
    for (int base = 0; base < nb; base += 256) {
        int v = (base + tid < nb) ? bsum[base + tid] : 0;
        sh[tid] = v;
        __syncthreads();
        for (int o = 1; o < 256; o <<= 1) {
            int t = (tid >= o) ? sh[tid - o] : 0;
            __syncthreads();
            sh[tid] += t;
            __syncthreads();
        }
        if (base + tid < nb) boff[base + tid] = carry + sh[tid] - v;
        __syncthreads();
        carry += sh[255];
        __syncthreads();
    }
}

__global__ __launch_bounds__(256) void scan_finalize_kernel(
        const int* __restrict__ deg, const int* __restrict__ incl,
        const int* __restrict__ boff, int* __restrict__ out,
        int* __restrict__ cursor, int N, int tailval) {
    int gid = blockIdx.x * 256 + threadIdx.x;
    if (gid < N) {
        int ex = boff[blockIdx.x] + incl[gid] - deg[gid];
        out[gid] = ex;
        cursor[gid] = ex;
    }
    if (gid == 0) out[N] = tailval;
}

// fill CSR. big mode: one 24-B record {src, dst, ef as 8 bf16} per slot,
// position computed WITHOUT atomics from off[d] + rank[e].
// R21: record stores are NONTEMPORAL (hint) — the 27 MB FETCH is pure RFO on
// partially-written lines; nt may skip allocate-on-write-miss. If counters
// don't move, fill is closed at its ~61 us scatter floor.
__global__ __launch_bounds__(256) void fill_kernel(
        const int* __restrict__ src, const int* __restrict__ dst,
        const void* __restrict__ ef, int* __restrict__ cursor,
        const int* __restrict__ rank, const int* __restrict__ off,
        int* __restrict__ eid, int* __restrict__ srcs,
        float* __restrict__ rec, int E, int big,
        const int* __restrict__ flagp) {
    int e = blockIdx.x * blockDim.x + threadIdx.x;
    if (e >= E) return;
    int d = dst[e];
    if (big) {
        int pos = off[d] + rank[e];
        unsigned p01, p23, p45, p67;
        if (*flagp) {
            const float4* p = (const float4*)ef + (size_t)e * 2;
            float4 a = p[0], b = p[1];
            p01 = pack2bf(a.x, a.y); p23 = pack2bf(a.z, a.w);
            p45 = pack2bf(b.x, b.y); p67 = pack2bf(b.z, b.w);
        } else {
            uint4 r = ((const uint4*)ef)[e];
            p01 = r.x; p23 = r.y; p45 = r.z; p67 = r.w;
        }
        unsigned long long* o = (unsigned long long*)(rec + (size_t)pos * 6);
        unsigned long long w0 = (unsigned long long)(unsigned)src[e]
                              | ((unsigned long long)(unsigned)d << 32);
        unsigned long long w1 = (unsigned long long)p01
                              | ((unsigned long long)p23 << 32);
        unsigned long long w2 = (unsigned long long)p45
                              | ((unsigned long long)p67 << 32);
        __builtin_nontemporal_store(w0, o);
        __builtin_nontemporal_store(w1, o + 1);
        __builtin_nontemporal_store(w2, o + 2);
    } else {
        int pos = atomicAdd(&cursor[d], 1);
        eid[pos] = e;
        srcs[pos] = src[e];
    }
}

// spans[i] = number of 64-slot waves node i's CSR segment touches
__global__ __launch_bounds__(256) void spans_kernel(
        const int* __restrict__ off, int* __restrict__ spans, int N) {
    int i = blockIdx.x * blockDim.x + threadIdx.x;
    if (i >= N) return;
    int k0 = off[i], k1 = off[i + 1];
    spans[i] = (k1 > k0) ? (((k1 - 1) >> 6) - (k0 >> 6) + 1) : 0;
}

// ---------------- MFMA nodeA: A[n] = h[n] @ Wm1 + bm  (A stored bf16, R19) ----------------
__global__ __launch_bounds__(256) void nodeA_mfma_kernel(
        const short* __restrict__ W1T, const float* __restrict__ bm,
        const float* __restrict__ h, unsigned short* __restrict__ Ab, int N) {
    __shared__ short lds_w[64 * 72];
    __shared__ short lds_x[4][64 * 72];
    const int tid = threadIdx.x, wid = tid >> 6, lane = tid & 63;
    const int r = lane & 15, q = lane >> 4;
    const int nb0 = blockIdx.x * 256 + wid * 64;

#pragma unroll
    for (int j = 0; j < 2; ++j) {
        int f8 = (tid * 2 + j) * 8;
        int row = f8 >> 6, k = f8 & 63;
        *(uint4*)&lds_w[row * 72 + k] = ((const uint4*)W1T)[tid * 2 + j];
    }
    short* xt = &lds_x[wid][0];
#pragma unroll 1
    for (int it = 0; it < 16; ++it) {
        int f4 = it * 64 + lane;
        int node = f4 >> 4, c4 = f4 & 15;
        int gn = nb0 + node; if (gn >= N) gn = N - 1;
        float4 v = ((const float4*)h)[(size_t)gn * 16 + c4];
        *(uint2*)&xt[node * 72 + c4 * 4] =
            make_uint2(pack2bf(v.x, v.y), pack2bf(v.z, v.w));
    }
    __syncthreads();

    bfrag bg[4][2];
#pragma unroll
    for (int ni = 0; ni < 4; ++ni)
#pragma unroll
        for (int ki = 0; ki < 2; ++ki)
            bg[ni][ki] = *(const bfrag*)&lds_w[(ni * 16 + r) * 72 + ki * 32 + q * 8];
    float buv[4];
#pragma unroll
    for (int ni = 0; ni < 4; ++ni) buv[ni] = bm[ni * 16 + r];

    ffrag C[4][4];
#pragma unroll
    for (int mi = 0; mi < 4; ++mi) {
        bfrag af[2];
#pragma unroll
        for (int ki = 0; ki < 2; ++ki)
            af[ki] = *(const bfrag*)&xt[(mi * 16 + r) * 72 + ki * 32 + q * 8];
#pragma unroll
        for (int ni = 0; ni < 4; ++ni) {
            ffrag c = {buv[ni], buv[ni], buv[ni], buv[ni]};
            c = __builtin_amdgcn_mfma_f32_16x16x32_bf16(af[0], bg[ni][0], c, 0, 0, 0);
            c = __builtin_amdgcn_mfma_f32_16x16x32_bf16(af[1], bg[ni][1], c, 0, 0, 0);
            C[mi][ni] = c;
        }
    }
#pragma unroll
    for (int mi = 0; mi < 4; ++mi)
#pragma unroll
        for (int rr = 0; rr < 4; ++rr) {
            int gn = nb0 + mi * 16 + q * 4 + rr;
            if (gn < N) {
#pragma unroll
                for (int ni = 0; ni < 4; ++ni)
                    Ab[(size_t)gn * 64 + ni * 16 + r] =
                        (unsigned short)f2bf_rne(C[mi][ni][rr]);
            }
        }
}

// ---------------- MFMA message (two-stage) + in-wave segmented reduction ----------------
// R12 structure (verified) + R17 shuffle-srow + R19 bf16 A gather.
__global__ __launch_bounds__(256, 4) void msg_mfma_red(
        const short* __restrict__ WeT, const float* __restrict__ be,
        const short* __restrict__ WbT, const float* __restrict__ rec,
        const unsigned short* __restrict__ Ab, float* __restrict__ pbuf,
        const int* __restrict__ off, const int* __restrict__ pstart, int E) {
    __shared__ short lds_ev[4][64 * 72];
    const int tid = threadIdx.x;
    const int wid = tid >> 6, lane = tid & 63;
    const int w = blockIdx.x * 4 + wid;
    if (w * 64 >= E) return;                 // wave fully out of range
    const int slot = w * 64 + lane;
    const int slotc = (slot < E) ? slot : (E - 1);

    // 24-B record: {src, dst, ef[8] bf16}
    const float* rbase = rec + (size_t)slotc * 6;
    uint2 u0 = *(const uint2*)rbase;         // src, dst
    uint2 u1 = *(const uint2*)(rbase + 2);   // ef01, ef23
    uint2 u2 = *(const uint2*)(rbase + 4);   // ef45, ef67
    int s  = (int)u0.x;
    int di = (int)u0.y;
    int pstv = pstart[di];
    int offv = off[di];

    const int r = lane & 15, q = lane >> 4;

    // per-(mi,rr) source rows via in-wave shuffle; issue ni=0 gather NOW
    int srow[16];
#pragma unroll
    for (int k = 0; k < 16; ++k)
        srow[k] = __shfl(s, (k >> 2) * 16 + q * 4 + (k & 3));   // k = mi*4+rr
    unsigned short cur[16];
#pragma unroll
    for (int k = 0; k < 16; ++k)
        cur[k] = Ab[(size_t)srow[k] * 64 + r];

    short* evb = &lds_ev[wid][0];
    short* evrow = evb + lane * 72;
    *(uint4*)(evrow) = make_uint4(u1.x, u1.y, u2.x, u2.y);
    uint4 z4 = make_uint4(0u, 0u, 0u, 0u);
    *(uint4*)(evrow + 8)  = z4;              // K-pad cols 8..31 = 0
    *(uint4*)(evrow + 16) = z4;
    *(uint4*)(evrow + 24) = z4;

    // ---- stage 1: EV^T = We^T @ EF^T + be (per-block), relu, pack to [edge][ch] ----
    bfrag afe[4];
#pragma unroll
    for (int mi = 0; mi < 4; ++mi)
        afe[mi] = *(const bfrag*)(evb + (mi * 16 + r) * 72 + q * 8);

#pragma unroll
    for (int ni = 0; ni < 4; ++ni) {
        bfrag bge = *(const bfrag*)(WeT + (ni * 16 + r) * 32 + q * 8);
        float4 b4 = *(const float4*)(be + ni * 16 + q * 4);
#pragma unroll
        for (int mi = 0; mi < 4; ++mi) {
            ffrag c = {b4.x, b4.y, b4.z, b4.w};
            c = __builtin_amdgcn_mfma_f32_16x16x32_bf16(bge, afe[mi], c, 0, 0, 0);
            unsigned lo = cvt_pk_bf16(fmaxf(c[0], 0.f), fmaxf(c[1], 0.f));
            unsigned hi = cvt_pk_bf16(fmaxf(c[2], 0.f), fmaxf(c[3], 0.f));
            *(uint2*)(evb + (mi * 16 + r) * 72 + ni * 16 + q * 4) =
                make_uint2(lo, hi);
        }
    }

    // ---- stage 2: M = EV @ Wm2 + A[src], relu, write transposed [ch][edge] ----
    bfrag af[4][2];
#pragma unroll
    for (int mi = 0; mi < 4; ++mi)
#pragma unroll
        for (int ki = 0; ki < 2; ++ki)
            af[mi][ki] = *(const bfrag*)(evb + (mi * 16 + r) * 72 + ki * 32 + q * 8);

#pragma unroll
    for (int ni = 0; ni < 4; ++ni) {
        unsigned short nxt[16];
        if (ni < 3) {
#pragma unroll
            for (int k = 0; k < 16; ++k)
                nxt[k] = Ab[(size_t)srow[k] * 64 + (ni + 1) * 16 + r];
        }
        bfrag bg0 = *(const bfrag*)(WbT + (ni * 16 + r) * 64 + q * 8);
        bfrag bg1 = *(const bfrag*)(WbT + (ni * 16 + r) * 64 + 32 + q * 8);
        ffrag C[4];
#pragma unroll
        for (int mi = 0; mi < 4; ++mi) {
            C[mi][0] = bf2f(cur[mi * 4 + 0]);
            C[mi][1] = bf2f(cur[mi * 4 + 1]);
            C[mi][2] = bf2f(cur[mi * 4 + 2]);
            C[mi][3] = bf2f(cur[mi * 4 + 3]);
        }
#pragma unroll
        for (int mi = 0; mi < 4; ++mi) {
            C[mi] = __builtin_amdgcn_mfma_f32_16x16x32_bf16(af[mi][0], bg0, C[mi], 0, 0, 0);
            C[mi] = __builtin_amdgcn_mfma_f32_16x16x32_bf16(af[mi][1], bg1, C[mi], 0, 0, 0);
        }
#pragma unroll
        for (int mi = 0; mi < 4; ++mi) {
            unsigned lo = cvt_pk_bf16(fmaxf(C[mi][0], 0.f), fmaxf(C[mi][1], 0.f));
            unsigned hi = cvt_pk_bf16(fmaxf(C[mi][2], 0.f), fmaxf(C[mi][3], 0.f));
            *(uint2*)(evb + (ni * 16 + r) * 72 + mi * 16 + q * 4) =
                make_uint2(lo, hi);
        }
        if (ni < 3) {
#pragma unroll
            for (int k = 0; k < 16; ++k) cur[k] = nxt[k];
        }
    }

    // ---- in-wave segmented reduction over edges (lane = channel) ----
    int kmax = E - w * 64; if (kmax > 64) kmax = 64;
    if (kmax < 64) {
        for (int k = kmax; k < 64; ++k) evb[lane * 72 + k] = 0;
    }
    int prevd = __shfl_up(di, 1);
    unsigned long long sm = __ballot(lane != 0 && di != prevd);
    int curp = __shfl(pstv, 0) + (w - (__shfl(offv, 0) >> 6));
    float acc = 0.f;
#pragma unroll
    for (int g = 0; g < 8; ++g) {
        uint4 v = *(const uint4*)(evb + lane * 72 + g * 8);
        float f0 = bflo(v.x), f1 = bfhi(v.x), f2 = bflo(v.y), f3 = bfhi(v.y);
        float f4 = bflo(v.z), f5 = bfhi(v.z), f6 = bflo(v.w), f7 = bfhi(v.w);
        unsigned gm = (unsigned)(sm >> (g * 8)) & 0xffu;
        if (gm == 0) {   // wave-uniform: no boundary in this 8-edge group
            acc += (((f0 + f1) + (f2 + f3)) + ((f4 + f5) + (f6 + f7)));
        } else {
            float fv[8] = {f0, f1, f2, f3, f4, f5, f6, f7};
#pragma unroll
            for (int j = 0; j < 8; ++j) {
                if (gm & (1u << j)) {
                    pbuf[(size_t)curp * 64 + lane] = acc;
                    acc = 0.f;
                    curp = __shfl(pstv, g * 8 + j);
                }
                acc += fv[j];
            }
        }
    }
    pbuf[(size_t)curp * 64 + lane] = acc;
}

// fixup: agg[i] = sum of node i's partial rows (R10, verified); zero for deg-0 nodes
__global__ __launch_bounds__(256) void fixup_kernel(
        const float* __restrict__ pbuf, const int* __restrict__ off,
        const int* __restrict__ pstart, float* __restrict__ agg, int N) {
    int tid = blockIdx.x * blockDim.x + threadIdx.x;
    int i = tid >> 2, q = tid & 3;
    if (i >= N) return;
    int k0 = off[i], k1 = off[i + 1];
    float acc[16];
#pragma unroll
    for (int c = 0; c < 16; ++c) acc[c] = 0.f;
    if (k1 > k0) {
        int nsp = ((k1 - 1) >> 6) - (k0 >> 6) + 1;
        int p = pstart[i];
        for (int j = 0; j < nsp; ++j) {
            const float4* pr = (const float4*)(pbuf + (size_t)(p + j) * 64 + q * 16);
#pragma unroll
            for (int c = 0; c < 4; ++c) {
                float4 v = pr[c];
                acc[4 * c] += v.x; acc[4 * c + 1] += v.y;
                acc[4 * c + 2] += v.z; acc[4 * c + 3] += v.w;
            }
        }
    }
    float4* o4 = (float4*)(agg + (size_t)i * 64 + q * 16);
#pragma unroll
    for (int c = 0; c < 4; ++c)
        o4[c] = make_float4(acc[4 * c], acc[4 * c + 1], acc[4 * c + 2], acc[4 * c + 3]);
}

// ---------------- MFMA update: h = relu([h,agg] @ Wu + bu) + h (R10, verified) ----------------
__global__ __launch_bounds__(128) void update_mfma_kernel(
        const short* __restrict__ WuT, const float* __restrict__ bu,
        float* __restrict__ h, const float* __restrict__ agg, int N) {
    __shared__ short lds_w[64 * 136];
    __shared__ short lds_x[2][64 * 136];
    const int tid = threadIdx.x, wid = tid >> 6, lane = tid & 63;
    const int r = lane & 15, q = lane >> 4;
    const int nb0 = blockIdx.x * 128 + wid * 64;
#pragma unroll
    for (int j = 0; j < 8; ++j) {
        int f8 = (tid * 8 + j) * 8;
        int row = f8 >> 7, k = f8 & 127;
        *(uint4*)&lds_w[row * 136 + k] = ((const uint4*)WuT)[tid * 8 + j];
    }
    short* xt = &lds_x[wid][0];
#pragma unroll 1
    for (int it = 0; it < 32; ++it) {
        int f4 = it * 64 + lane;
        int node = f4 >> 5, c4 = f4 & 31;
        int gn = nb0 + node; if (gn >= N) gn = N - 1;
        const float4* src = (c4 < 16)
            ? ((const float4*)h + (size_t)gn * 16 + c4)
            : ((const float4*)agg + (size_t)gn * 16 + (c4 - 16));
        float4 v = *src;
        *(uint2*)&xt[node * 136 + c4 * 4] =
            make_uint2(pack2bf(v.x, v.y), pack2bf(v.z, v.w));
    }
    __syncthreads();
    bfrag bg[4][4];
#pragma unroll
    for (int ni = 0; ni < 4; ++ni)
#pragma unroll
        for (int ki = 0; ki < 4; ++ki)
            bg[ni][ki] = *(const bfrag*)&lds_w[(ni * 16 + r) * 136 + ki * 32 + q * 8];
    float buv[4];
#pragma unroll
    for (int ni = 0; ni < 4; ++ni) buv[ni] = bu[ni * 16 + r];
    ffrag C[4][4];
#pragma unroll
    for (int mi = 0; mi < 4; ++mi) {
        bfrag af[4];
#pragma unroll
        for (int ki = 0; ki < 4; ++ki)
            af[ki] = *(const bfrag*)&xt[(mi * 16 + r) * 136 + ki * 32 + q * 8];
#pragma unroll
        for (int ni = 0; ni < 4; ++ni) {
            ffrag c = {buv[ni], buv[ni], buv[ni], buv[ni]};
#pragma unroll
            for (int ki = 0; ki < 4; ++ki)
                c = __builtin_amdgcn_mfma_f32_16x16x32_bf16(af[ki], bg[ni][ki], c, 0, 0, 0);
            C[mi][ni] = c;
        }
    }
#pragma unroll
    for (int mi = 0; mi < 4; ++mi)
#pragma unroll
        for (int rr = 0; rr < 4; ++rr) {
            int nl = mi * 16 + q * 4 + rr;
            int gn = nb0 + nl;
            if (gn < N) {
#pragma unroll
                for (int ni = 0; ni < 4; ++ni) {
                    float hold = bf2f((unsigned short)xt[nl * 136 + ni * 16 + r]);
                    h[(size_t)gn * 64 + ni * 16 + r] =
                        fmaxf(C[mi][ni][rr], 0.f) + hold;
                }
            }
        }
}

// ---------------- fallback gather (tiny ws; R3 structure; bf16 A) ----------------
__global__ __launch_bounds__(256) void gather_msg_fallback(
        const float* __restrict__ Wm2, const float* __restrict__ We,
        const float* __restrict__ be, const void* __restrict__ ef,
        const int* __restrict__ srcs, const int* __restrict__ eid,
        const int* __restrict__ off, const unsigned short* __restrict__ Ab,
        float* __restrict__ agg, int N, const int* __restrict__ flagp) {
    int i = blockIdx.x * blockDim.x + threadIdx.x;
    if (i >= N) return;
    int isf32 = *flagp;
    int k0 = off[i], k1 = off[i + 1];
    float acc[64];
#pragma unroll
    for (int c = 0; c < 64; ++c) acc[c] = 0.f;
    for (int k = k0; k < k1; ++k) {
        int s = srcs[k];
        int e = eid[k];
        const uint4* a4 = (const uint4*)(Ab + (size_t)s * 64);
        float t[64];
#pragma unroll
        for (int c = 0; c < 8; ++c) {
            uint4 v = a4[c];
            t[8 * c]     = bflo(v.x); t[8 * c + 1] = bfhi(v.x);
            t[8 * c + 2] = bflo(v.y); t[8 * c + 3] = bfhi(v.y);
            t[8 * c + 4] = bflo(v.z); t[8 * c + 5] = bfhi(v.z);
            t[8 * c + 6] = bflo(v.w); t[8 * c + 7] = bfhi(v.w);
        }
        float efv[8];
        if (isf32) {
            const float4* e4 = (const float4*)ef + (size_t)e * 2;
            float4 ra = e4[0], rb = e4[1];
            efv[0]=ra.x; efv[1]=ra.y; efv[2]=ra.z; efv[3]=ra.w;
            efv[4]=rb.x; efv[5]=rb.y; efv[6]=rb.z; efv[7]=rb.w;
        } else {
            uint4 rr = ((const uint4*)ef)[e];
            efv[0]=bflo(rr.x); efv[1]=bfhi(rr.x); efv[2]=bflo(rr.y); efv[3]=bfhi(rr.y);
            efv[4]=bflo(rr.z); efv[5]=bfhi(rr.z); efv[6]=bflo(rr.w); efv[7]=bfhi(rr.w);
        }
#pragma unroll 1
        for (int d0 = 0; d0 < 64; d0 += 8) {
            float ev[8];
#pragma unroll
            for (int dd = 0; dd < 8; ++dd) {
                float a = be[d0 + dd];
#pragma unroll
                for (int kk = 0; kk < 8; ++kk) a = fmaf(efv[kk], We[kk * 64 + d0 + dd], a);
                ev[dd] = fmaxf(a, 0.f);
            }
#pragma unroll
            for (int dd = 0; dd < 8; ++dd) {
                const float* w = Wm2 + (d0 + dd) * 64;
#pragma unroll
                for (int c = 0; c < 64; ++c) t[c] = fmaf(ev[dd], w[c], t[c]);
            }
        }
#pragma unroll
        for (int c = 0; c < 64; ++c) acc[c] += fmaxf(t[c], 0.f);
    }
    float4* o4 = (float4*)(agg + (size_t)i * 64);
#pragma unroll
    for (int c = 0; c < 16; ++c)
        o4[c] = make_float4(acc[4 * c], acc[4 * c + 1], acc[4 * c + 2], acc[4 * c + 3]);
}

// ---------------- MFMA scores: out[p] = relu([h_s|h_d]@Ws1+bs1) . Ws2 + bs2 ----------------
__global__ __launch_bounds__(128) void scores_mfma_kernel(
        const short* __restrict__ Ws1T, const float* __restrict__ bs1,
        const float* __restrict__ Ws2, const float* __restrict__ bs2,
        const int* __restrict__ ods, const int* __restrict__ odd,
        const float* __restrict__ h, void* __restrict__ out, int P,
        const int* __restrict__ flagp) {
    __shared__ short lds_w[64 * 136];
    __shared__ short lds_x[2][64 * 136];
    const int tid = threadIdx.x, wid = tid >> 6, lane = tid & 63;
    const int r = lane & 15, q = lane >> 4;
    const int pb0 = blockIdx.x * 128 + wid * 64;
#pragma unroll
    for (int j = 0; j < 8; ++j) {
        int f8 = (tid * 8 + j) * 8;
        int row = f8 >> 7, k = f8 & 127;
        *(uint4*)&lds_w[row * 136 + k] = ((const uint4*)Ws1T)[tid * 8 + j];
    }
    short* xt = &lds_x[wid][0];
#pragma unroll 1
    for (int it = 0; it < 32; ++it) {
        int f4 = it * 64 + lane;
        int pr = f4 >> 5, c4 = f4 & 31;
        int gp = pb0 + pr; if (gp >= P) gp = P - 1;
        int node = (c4 < 16) ? ods[gp] : odd[gp];
        int cc = (c4 < 16) ? c4 : (c4 - 16);
        float4 v = ((const float4*)h)[(size_t)node * 16 + cc];
        *(uint2*)&xt[pr * 136 + c4 * 4] =
            make_uint2(pack2bf(v.x, v.y), pack2bf(v.z, v.w));
    }
    __syncthreads();

    bfrag bg[4][4];
#pragma unroll
    for (int ni = 0; ni < 4; ++ni)
#pragma unroll
        for (int ki = 0; ki < 4; ++ki)
            bg[ni][ki] = *(const bfrag*)&lds_w[(ni * 16 + r) * 136 + ki * 32 + q * 8];
    float buv[4], w2v[4];
#pragma unroll
    for (int ni = 0; ni < 4; ++ni) { buv[ni] = bs1[ni * 16 + r]; w2v[ni] = Ws2[ni * 16 + r]; }
    int isf32 = *flagp;
    float b2 = bs2[0];

#pragma unroll
    for (int mi = 0; mi < 4; ++mi) {
        bfrag af[4];
#pragma unroll
        for (int ki = 0; ki < 4; ++ki)
            af[ki] = *(const bfrag*)&xt[(mi * 16 + r) * 136 + ki * 32 + q * 8];
        float part[4] = {0.f, 0.f, 0.f, 0.f};
#pragma unroll
        for (int ni = 0; ni < 4; ++ni) {
            ffrag c = {buv[ni], buv[ni], buv[ni], buv[ni]};
#pragma unroll
            for (int ki = 0; ki < 4; ++ki)
                c = __builtin_amdgcn_mfma_f32_16x16x32_bf16(af[ki], bg[ni][ki], c, 0, 0, 0);
#pragma unroll
            for (int rr = 0; rr < 4; ++rr)
                part[rr] = fmaf(fmaxf(c[rr], 0.f), w2v[ni], part[rr]);
        }
#pragma unroll
        for (int rr = 0; rr < 4; ++rr) {
            float v = part[rr];
            v += __shfl_xor(v, 1); v += __shfl_xor(v, 2);
            v += __shfl_xor(v, 4); v += __shfl_xor(v, 8);
            if (r == 0) {
                int p = pb0 + mi * 16 + q * 4 + rr;
                if (p < P) {
                    float score = v + b2;
                    if (isf32) ((float*)out)[p] = score;
                    else ((__hip_bfloat16*)out)[p] = __float2bfloat16(score);
                }
            }
        }
    }
}

// ---------------- graph embed ----------------
__global__ __launch_bounds__(256) void embed_kernel(
        const float* __restrict__ h, float* __restrict__ gsum, int N) {
    __shared__ float red[256];
    int c = threadIdx.x & 63;
    int sub = threadIdx.x >> 6;   // 0..3
    float a = 0.f;
    for (int i = blockIdx.x * 4 + sub; i < N; i += gridDim.x * 4)
        a += h[(size_t)i * 64 + c];
    red[threadIdx.x] = a;
    __syncthreads();
    if (threadIdx.x < 64) {
        float t = red[threadIdx.x] + red[threadIdx.x + 64] +
                  red[threadIdx.x + 128] + red[threadIdx.x + 192];
        unsafeAtomicAdd(&gsum[threadIdx.x], t);
    }
}

// ---------------- dynamic-K head (wave-parallel; R14 verified) ----------------
__global__ void khead_kernel(const float* __restrict__ ws,
                             void* __restrict__ out, int N, int P,
                             const int* __restrict__ flagp) {
    __shared__ float sh1[32];
    __shared__ float sh2[16];
    int lane = threadIdx.x;   // 64 threads, 1 wave
    float invN = 1.f / (float)N;
    float a1 = (lane < 32) ? ws[OFF_BK1 + lane] : 0.f;
#pragma unroll
    for (int i = 0; i < 68; ++i) {
        float xi = (i < 64) ? ws[OFF_GSUM + i] * invN : ws[OFF_TS + i - 64];
        if (lane < 32) a1 = fmaf(xi, ws[OFF_WK1 + i * 32 + lane], a1);
    }
    if (lane < 32) sh1[lane] = fmaxf(a1, 0.f);
    __syncthreads();
    float a2 = (lane < 16) ? ws[OFF_BK2 + lane] : 0.f;
#pragma unroll
    for (int j = 0; j < 32; ++j) {
        if (lane < 16) a2 = fmaf(sh1[j], ws[OFF_WK2 + j * 16 + lane], a2);
    }
    if (lane < 16) sh2[lane] = fmaxf(a2, 0.f);
    __syncthreads();
    if (lane == 0) {
        float raw = ws[OFF_BK3];
#pragma unroll
        for (int k2 = 0; k2 < 16; ++k2) raw = fmaf(sh2[k2], ws[OFF_WK3 + k2], raw);
        float sig = 1.f / (1.f + expf(-raw));
        float k = 1.f + 49.f * sig;
        if (*flagp) ((float*)out)[P] = k;
        else ((__hip_bfloat16*)out)[P] = __float2bfloat16(k);
    }
}

extern "C" void kernel_launch(void* const* d_in, const int* in_sizes, int n_in,
                              void* d_out, int out_size, void* d_ws, size_t ws_size,
                              hipStream_t stream) {
    const void* nf = d_in[0];
    const int*  ei = (const int*)d_in[1];
    const void* ef = d_in[2];
    const int*  od = (const int*)d_in[3];
    float* ws = (float*)d_ws;

    const int N = in_sizes[0] / 16;   // 50000
    const int E = in_sizes[1] / 2;    // 1200000
    const int P = in_sizes[3] / 2;    // 10000

    // layout: h, agg, A(bf16); deg/spans, off, cursor, pstart, eid, srcs, Wtrans, rank; rec; pbuf
    float* h      = ws + OFF_H;
    float* agg    = h + (size_t)N * 64;
    unsigned short* Ab = (unsigned short*)(agg + (size_t)N * 64);  // N*64 bf16 (half the f32 slot)
    int*   deg    = (int*)(agg + (size_t)N * 64 + (size_t)N * 32); // N (reused as spans)
    int*   off    = deg + N;                      // N+1
    int*   cursor = off + N + 1;                  // N
    int*   pstart = cursor + N;                   // N+1
    int*   eid    = pstart + N + 1;               // E (fallback only)
    int*   srcs   = eid + E;                      // E (fallback only)
    short* WbT    = (short*)(srcs + E);           // 59392 shorts: WbT|W1T|WuT|WeT|Ws1T
    short* W1T    = WbT + 12288;
    short* WuT    = WbT + 24576;
    short* WeT    = WbT + 49152;
    short* Ws1T   = WbT + 51200;
    int*   rank   = (int*)(WbT + 59392);          // E (big path only)
    int*   flag   = (int*)(ws + OFF_FLAG);
    int*   bsum   = (int*)(ws + OFF_BSUM);
    int*   boff   = (int*)(ws + OFF_BOFF);

    size_t fsofar = (size_t)OFF_H + 2 * (size_t)N * 64 + (size_t)N * 32
                  + (size_t)(N + (N + 1) + N + (N + 1) + E + E + E) + 29696;
    size_t recOff = (fsofar + 7) & ~(size_t)7;            // record base align
    float* rec = ws + recOff;
    size_t pbufOff = recOff + (size_t)E * 6;
    float* pbuf = ws + pbufOff;
    long pbufRows = (long)N + E / 64 + 128;
    size_t needBytes = (pbufOff + (size_t)pbufRows * 64) * sizeof(float);
    const bool big = (ws_size >= needBytes);

    const int* srcv = ei;
    const int* dstv = ei + E;

    // 0. dtype detect
    detect_dtype_kernel<<<1, 64, 0, stream>>>((const unsigned short*)nf, flag);

    // 1. convert weights to f32 in ws; build transposed bf16 weights
    ConvArgs ca;
    const int srcidx[19] = {5, 6, 7, 8, 9, 10, 11, 12, 13, 14, 15, 16, 17, 18, 19, 20, 21, 22, 4};
    const int wsoff[19]  = {OFF_WN, OFF_BN, OFF_WE, OFF_BE, OFF_WM, OFF_BM, OFF_WU, OFF_BU,
                            OFF_WS1, OFF_BS1, OFF_WS2, OFF_BS2, OFF_WK1, OFF_BK1, OFF_WK2,
                            OFF_BK2, OFF_WK3, OFF_BK3, OFF_TS};
    int maxn = 0;
    for (int i = 0; i < 19; ++i) {
        ca.src[i] = d_in[srcidx[i]];
        ca.off[i] = wsoff[i];
        ca.n[i]   = in_sizes[srcidx[i]];
        if (ca.n[i] > maxn) maxn = ca.n[i];
    }
    dim3 cgrid((maxn + 255) / 256, 19);
    convert_all_kernel<<<cgrid, 256, 0, stream>>>(ca, ws, flag);
    wtrans_prep_kernel<<<232, 256, 0, stream>>>(ws, WbT);

    // 2. node projection
    node_proj_kernel<<<(N * 64 + 255) / 256, 256, 0, stream>>>(nf, ws, h, N, flag);

    // 3. build CSR by dst (once). count records per-edge rank so fill
    //    needs no atomics in big mode.
    hipMemsetAsync(deg, 0, (size_t)N * sizeof(int), stream);
    count_kernel<<<(E + 255) / 256, 256, 0, stream>>>(dstv, deg, rank, E, big ? 1 : 0);
    int nb = (N + 255) / 256;
    scan_blocks_kernel<<<nb, 256, 0, stream>>>(deg, cursor, bsum, N);
    scan_bsum_kernel<<<1, 256, 0, stream>>>(bsum, boff, nb);
    scan_finalize_kernel<<<nb, 256, 0, stream>>>(deg, cursor, boff, off, cursor, N, E);
    fill_kernel<<<(E + 255) / 256, 256, 0, stream>>>(
        srcv, dstv, ef, cursor, rank, off, eid, srcs, rec, E, big ? 1 : 0, flag);

    // 3b. pstart = exclusive scan of wave-span counts (big path only)
    if (big) {
        spans_kernel<<<nb, 256, 0, stream>>>(off, deg, N);       // deg := spans
        scan_blocks_kernel<<<nb, 256, 0, stream>>>(deg, cursor, bsum, N);
        scan_bsum_kernel<<<1, 256, 0, stream>>>(bsum, boff, nb);
        scan_finalize_kernel<<<nb, 256, 0, stream>>>(deg, cursor, boff, pstart, cursor, N, 0);
    }

    // 4. GNN layers (R19 structure: nodeA -> msg -> fixup -> update; R20 fuse reverted)
    const int N4 = N * 4;
    const int mblocks = (E + 255) / 256;
    const int ablocks = (N + 255) / 256;
    const int ublocks = (N + 127) / 128;
    for (int l = 0; l < 3; ++l) {
        nodeA_mfma_kernel<<<ablocks, 256, 0, stream>>>(
            W1T + l * 4096, ws + OFF_BM + l * 64, h, Ab, N);
        if (big) {
            msg_mfma_red<<<mblocks, 256, 0, stream>>>(
                WeT, ws + OFF_BE, WbT + l * 4096, rec, Ab, pbuf, off, pstart, E);
            fixup_kernel<<<(N4 + 255) / 256, 256, 0, stream>>>(
                pbuf, off, pstart, agg, N);
        } else {
            const float* Wm2 = ws + OFF_WM + l * 8192 + 4096;
            gather_msg_fallback<<<(N + 255) / 256, 256, 0, stream>>>(
                Wm2, ws + OFF_WE, ws + OFF_BE, ef, srcs, eid, off, Ab, agg, N, flag);
        }
        update_mfma_kernel<<<ublocks, 128, 0, stream>>>(
            WuT + l * 8192, ws + OFF_BU + l * 64, h, agg, N);
    }

    // 5. per-flow scores (MFMA)
    scores_mfma_kernel<<<(P + 127) / 128, 128, 0, stream>>>(
        Ws1T, ws + OFF_BS1, ws + OFF_WS2, ws + OFF_BS2,
        od, od + P, h, d_out, P, flag);

    // 6. graph embedding + dynamic-K head
    hipMemsetAsync(ws + OFF_GSUM, 0, 64 * sizeof(float), stream);
    embed_kernel<<<256, 256, 0, stream>>>(h, ws + OFF_GSUM, N);
    khead_kernel<<<1, 64, 0, stream>>>(ws, d_out, N, P, flag);
}

// Round 11
// 541.399 us; speedup vs baseline: 1.1578x; 1.0802x over previous
//
#include <hip/hip_runtime.h>
#include <hip/hip_bf16.h>

// ---------------- workspace layout (float offsets, fixed small region) ----------------
#define OFF_WN   0
#define OFF_BN   1024
#define OFF_WE   1088
#define OFF_BE   1600
#define OFF_WM   1664            // 3 * 128 * 64
#define OFF_BM   26240           // 3 * 64
#define OFF_WU   26432           // 3 * 128 * 64
#define OFF_BU   51008           // 3 * 64
#define OFF_WS1  51200           // 128 * 64
#define OFF_BS1  59392
#define OFF_WS2  59456
#define OFF_BS2  59520
#define OFF_WK1  59521           // 68 * 32
#define OFF_BK1  61697
#define OFF_WK2  61729           // 32 * 16
#define OFF_BK2  62241
#define OFF_WK3  62257
#define OFF_BK3  62273
#define OFF_TS   62274           // traffic stats (4)
#define OFF_GSUM 62278           // graph-embed accumulator (64)
#define OFF_FLAG 62344           // dtype flag: 1 = inputs are f32, 0 = bf16
#define OFF_BSUM 62400           // block sums for scan (<=400)
#define OFF_BOFF 62900           // block offsets for scan (<=400)
#define OFF_H    65536           // big arrays start here (see kernel_launch)

typedef __attribute__((ext_vector_type(8))) short bfrag;   // 8 bf16 (4 VGPRs)
typedef __attribute__((ext_vector_type(4))) float ffrag;   // 4 f32 acc

__device__ __forceinline__ float bf2f(unsigned short u) {
    unsigned int i = ((unsigned int)u) << 16;
    float f;
    __builtin_memcpy(&f, &i, sizeof(f));
    return f;
}
__device__ __forceinline__ float bflo(unsigned int u) {
    unsigned int i = u << 16;
    float f; __builtin_memcpy(&f, &i, sizeof(f)); return f;
}
__device__ __forceinline__ float bfhi(unsigned int u) {
    unsigned int i = u & 0xffff0000u;
    float f; __builtin_memcpy(&f, &i, sizeof(f)); return f;
}
__device__ __forceinline__ unsigned int f2bf_rne(float f) {
    unsigned int u; __builtin_memcpy(&u, &f, 4);
    return (u + 0x7fffu + ((u >> 16) & 1u)) >> 16;
}
__device__ __forceinline__ unsigned int pack2bf(float a, float b) {
    return f2bf_rne(a) | (f2bf_rne(b) << 16);
}
// hardware packed f32->bf16 (RNE), a -> low half, b -> high half
__device__ __forceinline__ unsigned int cvt_pk_bf16(float a, float b) {
    unsigned int r;
    asm("v_cvt_pk_bf16_f32 %0, %1, %2" : "=v"(r) : "v"(a), "v"(b));
    return r;
}

// ---------------- dtype sniffer (R2 evidence: takes the f32 branch) ----------------
__global__ void detect_dtype_kernel(const unsigned short* __restrict__ nf,
                                    int* __restrict__ flag) {
    int t = threadIdx.x;  // 64 threads
    float m = 0.f;
    for (int i = t; i < 1024; i += 64) {
        float v = fabsf(bf2f(nf[i]));
        if (!isnan(v)) m = fmaxf(m, v);
        else m = 1e30f;
    }
    for (int o = 32; o > 0; o >>= 1) m = fmaxf(m, __shfl_down(m, o));
    if (t == 0) flag[0] = (m > 1e6f) ? 1 : 0;
}

// ---------------- weight conversion ----------------
struct ConvArgs {
    const void* src[19];
    int off[19];
    int n[19];
};

__global__ __launch_bounds__(256) void convert_all_kernel(
        ConvArgs a, float* __restrict__ ws, const int* __restrict__ flagp) {
    int isf32 = *flagp;
    int ai = blockIdx.y;
    int i  = blockIdx.x * blockDim.x + threadIdx.x;
    if (i < a.n[ai]) {
        float v = isf32 ? ((const float*)a.src[ai])[i]
                        : bf2f(((const unsigned short*)a.src[ai])[i]);
        ws[a.off[ai] + i] = v;
    }
}

// ---------------- transposed bf16 weight prep ----------------
// WbT[l][n*64+k]  = Wm2[l][k][n]         (12288 shorts)
// W1T[l][n*64+k]  = Wm1[l][k][n]         (12288 shorts)
// WuT[l][n*128+k] = Wu[l][k][n]          (24576 shorts)
// WeT[n*32+k]     = k<8 ? We[k][n] : 0   (2048 shorts, zero-padded K)
// Ws1T[n*128+k]   = Ws1[k][n]            (8192 shorts)
__global__ __launch_bounds__(256) void wtrans_prep_kernel(
        const float* __restrict__ ws, short* __restrict__ Wb) {
    int idx = blockIdx.x * 256 + threadIdx.x;
    if (idx < 12288) {
        int l = idx >> 12, rem = idx & 4095, n = rem >> 6, k = rem & 63;
        Wb[idx] = (short)f2bf_rne(ws[OFF_WM + l * 8192 + 4096 + k * 64 + n]);
    } else if (idx < 24576) {
        int j = idx - 12288;
        int l = j >> 12, rem = j & 4095, n = rem >> 6, k = rem & 63;
        Wb[idx] = (short)f2bf_rne(ws[OFF_WM + l * 8192 + k * 64 + n]);
    } else if (idx < 49152) {
        int j = idx - 24576;
        int l = j >> 13, rem = j & 8191, n = rem >> 7, k = rem & 127;
        Wb[idx] = (short)f2bf_rne(ws[OFF_WU + l * 8192 + k * 64 + n]);
    } else if (idx < 51200) {
        int j = idx - 49152;
        int n = j >> 5, k = j & 31;
        Wb[idx] = (k < 8) ? (short)f2bf_rne(ws[OFF_WE + k * 64 + n]) : (short)0;
    } else if (idx < 59392) {
        int j = idx - 51200;
        int n = j >> 7, k = j & 127;
        Wb[idx] = (short)f2bf_rne(ws[OFF_WS1 + k * 64 + n]);
    }
}

// ---------------- node projection: h = relu(nf @ Wn + bn) ----------------
__global__ __launch_bounds__(256) void node_proj_kernel(
        const void* __restrict__ nf, const float* __restrict__ ws,
        float* __restrict__ h, int N, const int* __restrict__ flagp) {
    int idx = blockIdx.x * blockDim.x + threadIdx.x;
    if (idx >= N * 64) return;
    int isf32 = *flagp;
    int i = idx >> 6, c = idx & 63;
    const float* Wn = ws + OFF_WN;
    float acc = ws[OFF_BN + c];
    float x[16];
    if (isf32) {
        const float* row = (const float*)nf + (size_t)i * 16;
#pragma unroll
        for (int k = 0; k < 16; ++k) x[k] = row[k];
    } else {
        const unsigned short* row = (const unsigned short*)nf + (size_t)i * 16;
#pragma unroll
        for (int k = 0; k < 16; ++k) x[k] = bf2f(row[k]);
    }
#pragma unroll
    for (int k = 0; k < 16; ++k) acc = fmaf(x[k], Wn[k * 64 + c], acc);
    h[idx] = fmaxf(acc, 0.f);
}

// ---------------- CSR build ----------------
// count also records each edge's rank within its dst bucket (coalesced
// stream write) so fill needs NO atomics: pos = off[d] + rank[e].
__global__ __launch_bounds__(256) void count_kernel(
        const int* __restrict__ dst, int* __restrict__ deg,
        int* __restrict__ rank, int E, int dorank) {
    int e = blockIdx.x * blockDim.x + threadIdx.x;
    if (e < E) {
        int r = atomicAdd(&deg[dst[e]], 1);
        if (dorank) rank[e] = r;
    }
}

__global__ __launch_bounds__(256) void scan_blocks_kernel(
        const int* __restrict__ deg, int* __restrict__ incl,
        int* __restrict__ bsum, int N) {
    int tid = threadIdx.x;
    int gid = blockIdx.x * 256 + tid;
    int v = (gid < N) ? deg[gid] : 0;
    int lane = tid & 63, w = tid >> 6;
    int x = v;
#pragma unroll
    for (int o = 1; o < 64; o <<= 1) {
        int y = __shfl_up(x, o);
        if (lane >= o) x += y;
    }
    __shared__ int wsum[4];
    __shared__ int woff[4];
    if (lane == 63) wsum[w] = x;
    __syncthreads();
    if (tid == 0) {
        int a = 0;
#pragma unroll
        for (int i = 0; i < 4; ++i) { woff[i] = a; a += wsum[i]; }
    }
    __syncthreads();
    x += woff[w];
    if (gid < N) incl[gid] = x;
    if (tid == 255) bsum[blockIdx.x] = x;
}

__global__ __launch_bounds__(256) void scan_bsum_kernel(
        const int* __restrict__ bsum, int* __restrict__ boff, int nb) {
    __shared__ int sh[256];
    int tid = threadIdx.x;
    int carry = 0;
    for (int base = 0; base < nb; base += 256) {
        int v = (base + tid < nb) ? bsum[base + tid] : 0;
        sh[tid] = v;
        __syncthreads();
        for (int o = 1; o < 256; o <<= 1) {
            int t = (tid >= o) ? sh[tid - o] : 0;
            __syncthreads();
            sh[tid] += t;
            __syncthreads();
        }
        if (base + tid < nb) boff[base + tid] = carry + sh[tid] - v;
        __syncthreads();
        carry += sh[255];
        __syncthreads();
    }
}

__global__ __launch_bounds__(256) void scan_finalize_kernel(
        const int* __restrict__ deg, const int* __restrict__ incl,
        const int* __restrict__ boff, int* __restrict__ out,
        int* __restrict__ cursor, int N, int tailval) {
    int gid = blockIdx.x * 256 + threadIdx.x;
    if (gid < N) {
        int ex = boff[blockIdx.x] + incl[gid] - deg[gid];
        out[gid] = ex;
        cursor[gid] = ex;
    }
    if (gid == 0) out[N] = tailval;
}

// fill CSR. big mode: one 24-B record {src, dst, ef as 8 bf16} per slot,
// position computed WITHOUT atomics from off[d] + rank[e].
// CLOSED at ~61 us: plain stores + L2 partial merge. 2-pass reorder (R16/R18)
// and nontemporal stores (R21: 62->100 us, WRITE +21 MB) both regressed.
__global__ __launch_bounds__(256) void fill_kernel(
        const int* __restrict__ src, const int* __restrict__ dst,
        const void* __restrict__ ef, int* __restrict__ cursor,
        const int* __restrict__ rank, const int* __restrict__ off,
        int* __restrict__ eid, int* __restrict__ srcs,
        float* __restrict__ rec, int E, int big,
        const int* __restrict__ flagp) {
    int e = blockIdx.x * blockDim.x + threadIdx.x;
    if (e >= E) return;
    int d = dst[e];
    if (big) {
        int pos = off[d] + rank[e];
        unsigned p01, p23, p45, p67;
        if (*flagp) {
            const float4* p = (const float4*)ef + (size_t)e * 2;
            float4 a = p[0], b = p[1];
            p01 = pack2bf(a.x, a.y); p23 = pack2bf(a.z, a.w);
            p45 = pack2bf(b.x, b.y); p67 = pack2bf(b.z, b.w);
        } else {
            uint4 r = ((const uint4*)ef)[e];
            p01 = r.x; p23 = r.y; p45 = r.z; p67 = r.w;
        }
        float* o = rec + (size_t)pos * 6;
        *(uint2*)o       = make_uint2((unsigned)src[e], (unsigned)d);
        *(uint2*)(o + 2) = make_uint2(p01, p23);
        *(uint2*)(o + 4) = make_uint2(p45, p67);
    } else {
        int pos = atomicAdd(&cursor[d], 1);
        eid[pos] = e;
        srcs[pos] = src[e];
    }
}

// spans[i] = number of 64-slot waves node i's CSR segment touches
__global__ __launch_bounds__(256) void spans_kernel(
        const int* __restrict__ off, int* __restrict__ spans, int N) {
    int i = blockIdx.x * blockDim.x + threadIdx.x;
    if (i >= N) return;
    int k0 = off[i], k1 = off[i + 1];
    spans[i] = (k1 > k0) ? (((k1 - 1) >> 6) - (k0 >> 6) + 1) : 0;
}

// ---------------- MFMA nodeA: A[n] = h[n] @ Wm1 + bm  (A stored bf16, R19) ----------------
__global__ __launch_bounds__(256) void nodeA_mfma_kernel(
        const short* __restrict__ W1T, const float* __restrict__ bm,
        const float* __restrict__ h, unsigned short* __restrict__ Ab, int N) {
    __shared__ short lds_w[64 * 72];
    __shared__ short lds_x[4][64 * 72];
    const int tid = threadIdx.x, wid = tid >> 6, lane = tid & 63;
    const int r = lane & 15, q = lane >> 4;
    const int nb0 = blockIdx.x * 256 + wid * 64;

#pragma unroll
    for (int j = 0; j < 2; ++j) {
        int f8 = (tid * 2 + j) * 8;
        int row = f8 >> 6, k = f8 & 63;
        *(uint4*)&lds_w[row * 72 + k] = ((const uint4*)W1T)[tid * 2 + j];
    }
    short* xt = &lds_x[wid][0];
#pragma unroll 1
    for (int it = 0; it < 16; ++it) {
        int f4 = it * 64 + lane;
        int node = f4 >> 4, c4 = f4 & 15;
        int gn = nb0 + node; if (gn >= N) gn = N - 1;
        float4 v = ((const float4*)h)[(size_t)gn * 16 + c4];
        *(uint2*)&xt[node * 72 + c4 * 4] =
            make_uint2(pack2bf(v.x, v.y), pack2bf(v.z, v.w));
    }
    __syncthreads();

    bfrag bg[4][2];
#pragma unroll
    for (int ni = 0; ni < 4; ++ni)
#pragma unroll
        for (int ki = 0; ki < 2; ++ki)
            bg[ni][ki] = *(const bfrag*)&lds_w[(ni * 16 + r) * 72 + ki * 32 + q * 8];
    float buv[4];
#pragma unroll
    for (int ni = 0; ni < 4; ++ni) buv[ni] = bm[ni * 16 + r];

    ffrag C[4][4];
#pragma unroll
    for (int mi = 0; mi < 4; ++mi) {
        bfrag af[2];
#pragma unroll
        for (int ki = 0; ki < 2; ++ki)
            af[ki] = *(const bfrag*)&xt[(mi * 16 + r) * 72 + ki * 32 + q * 8];
#pragma unroll
        for (int ni = 0; ni < 4; ++ni) {
            ffrag c = {buv[ni], buv[ni], buv[ni], buv[ni]};
            c = __builtin_amdgcn_mfma_f32_16x16x32_bf16(af[0], bg[ni][0], c, 0, 0, 0);
            c = __builtin_amdgcn_mfma_f32_16x16x32_bf16(af[1], bg[ni][1], c, 0, 0, 0);
            C[mi][ni] = c;
        }
    }
#pragma unroll
    for (int mi = 0; mi < 4; ++mi)
#pragma unroll
        for (int rr = 0; rr < 4; ++rr) {
            int gn = nb0 + mi * 16 + q * 4 + rr;
            if (gn < N) {
#pragma unroll
                for (int ni = 0; ni < 4; ++ni)
                    Ab[(size_t)gn * 64 + ni * 16 + r] =
                        (unsigned short)f2bf_rne(C[mi][ni][rr]);
            }
        }
}

// ---------------- MFMA message (two-stage) + in-wave segmented reduction ----------------
// R12 structure (verified) + R17 shuffle-srow + R19 bf16 A gather.
__global__ __launch_bounds__(256, 4) void msg_mfma_red(
        const short* __restrict__ WeT, const float* __restrict__ be,
        const short* __restrict__ WbT, const float* __restrict__ rec,
        const unsigned short* __restrict__ Ab, float* __restrict__ pbuf,
        const int* __restrict__ off, const int* __restrict__ pstart, int E) {
    __shared__ short lds_ev[4][64 * 72];
    const int tid = threadIdx.x;
    const int wid = tid >> 6, lane = tid & 63;
    const int w = blockIdx.x * 4 + wid;
    if (w * 64 >= E) return;                 // wave fully out of range
    const int slot = w * 64 + lane;
    const int slotc = (slot < E) ? slot : (E - 1);

    // 24-B record: {src, dst, ef[8] bf16}
    const float* rbase = rec + (size_t)slotc * 6;
    uint2 u0 = *(const uint2*)rbase;         // src, dst
    uint2 u1 = *(const uint2*)(rbase + 2);   // ef01, ef23
    uint2 u2 = *(const uint2*)(rbase + 4);   // ef45, ef67
    int s  = (int)u0.x;
    int di = (int)u0.y;
    int pstv = pstart[di];
    int offv = off[di];

    const int r = lane & 15, q = lane >> 4;

    // per-(mi,rr) source rows via in-wave shuffle; issue ni=0 gather NOW
    int srow[16];
#pragma unroll
    for (int k = 0; k < 16; ++k)
        srow[k] = __shfl(s, (k >> 2) * 16 + q * 4 + (k & 3));   // k = mi*4+rr
    unsigned short cur[16];
#pragma unroll
    for (int k = 0; k < 16; ++k)
        cur[k] = Ab[(size_t)srow[k] * 64 + r];

    short* evb = &lds_ev[wid][0];
    short* evrow = evb + lane * 72;
    *(uint4*)(evrow) = make_uint4(u1.x, u1.y, u2.x, u2.y);
    uint4 z4 = make_uint4(0u, 0u, 0u, 0u);
    *(uint4*)(evrow + 8)  = z4;              // K-pad cols 8..31 = 0
    *(uint4*)(evrow + 16) = z4;
    *(uint4*)(evrow + 24) = z4;

    // ---- stage 1: EV^T = We^T @ EF^T + be (per-block), relu, pack to [edge][ch] ----
    bfrag afe[4];
#pragma unroll
    for (int mi = 0; mi < 4; ++mi)
        afe[mi] = *(const bfrag*)(evb + (mi * 16 + r) * 72 + q * 8);

#pragma unroll
    for (int ni = 0; ni < 4; ++ni) {
        bfrag bge = *(const bfrag*)(WeT + (ni * 16 + r) * 32 + q * 8);
        float4 b4 = *(const float4*)(be + ni * 16 + q * 4);
#pragma unroll
        for (int mi = 0; mi < 4; ++mi) {
            ffrag c = {b4.x, b4.y, b4.z, b4.w};
            c = __builtin_amdgcn_mfma_f32_16x16x32_bf16(bge, afe[mi], c, 0, 0, 0);
            unsigned lo = cvt_pk_bf16(fmaxf(c[0], 0.f), fmaxf(c[1], 0.f));
            unsigned hi = cvt_pk_bf16(fmaxf(c[2], 0.f), fmaxf(c[3], 0.f));
            *(uint2*)(evb + (mi * 16 + r) * 72 + ni * 16 + q * 4) =
                make_uint2(lo, hi);
        }
    }

    // ---- stage 2: M = EV @ Wm2 + A[src], relu, write transposed [ch][edge] ----
    bfrag af[4][2];
#pragma unroll
    for (int mi = 0; mi < 4; ++mi)
#pragma unroll
        for (int ki = 0; ki < 2; ++ki)
            af[mi][ki] = *(const bfrag*)(evb + (mi * 16 + r) * 72 + ki * 32 + q * 8);

#pragma unroll
    for (int ni = 0; ni < 4; ++ni) {
        unsigned short nxt[16];
        if (ni < 3) {
#pragma unroll
            for (int k = 0; k < 16; ++k)
                nxt[k] = Ab[(size_t)srow[k] * 64 + (ni + 1) * 16 + r];
        }
        bfrag bg0 = *(const bfrag*)(WbT + (ni * 16 + r) * 64 + q * 8);
        bfrag bg1 = *(const bfrag*)(WbT + (ni * 16 + r) * 64 + 32 + q * 8);
        ffrag C[4];
#pragma unroll
        for (int mi = 0; mi < 4; ++mi) {
            C[mi][0] = bf2f(cur[mi * 4 + 0]);
            C[mi][1] = bf2f(cur[mi * 4 + 1]);
            C[mi][2] = bf2f(cur[mi * 4 + 2]);
            C[mi][3] = bf2f(cur[mi * 4 + 3]);
        }
#pragma unroll
        for (int mi = 0; mi < 4; ++mi) {
            C[mi] = __builtin_amdgcn_mfma_f32_16x16x32_bf16(af[mi][0], bg0, C[mi], 0, 0, 0);
            C[mi] = __builtin_amdgcn_mfma_f32_16x16x32_bf16(af[mi][1], bg1, C[mi], 0, 0, 0);
        }
#pragma unroll
        for (int mi = 0; mi < 4; ++mi) {
            unsigned lo = cvt_pk_bf16(fmaxf(C[mi][0], 0.f), fmaxf(C[mi][1], 0.f));
            unsigned hi = cvt_pk_bf16(fmaxf(C[mi][2], 0.f), fmaxf(C[mi][3], 0.f));
            *(uint2*)(evb + (ni * 16 + r) * 72 + mi * 16 + q * 4) =
                make_uint2(lo, hi);
        }
        if (ni < 3) {
#pragma unroll
            for (int k = 0; k < 16; ++k) cur[k] = nxt[k];
        }
    }

    // ---- in-wave segmented reduction over edges (lane = channel) ----
    int kmax = E - w * 64; if (kmax > 64) kmax = 64;
    if (kmax < 64) {
        for (int k = kmax; k < 64; ++k) evb[lane * 72 + k] = 0;
    }
    int prevd = __shfl_up(di, 1);
    unsigned long long sm = __ballot(lane != 0 && di != prevd);
    int curp = __shfl(pstv, 0) + (w - (__shfl(offv, 0) >> 6));
    float acc = 0.f;
#pragma unroll
    for (int g = 0; g < 8; ++g) {
        uint4 v = *(const uint4*)(evb + lane * 72 + g * 8);
        float f0 = bflo(v.x), f1 = bfhi(v.x), f2 = bflo(v.y), f3 = bfhi(v.y);
        float f4 = bflo(v.z), f5 = bfhi(v.z), f6 = bflo(v.w), f7 = bfhi(v.w);
        unsigned gm = (unsigned)(sm >> (g * 8)) & 0xffu;
        if (gm == 0) {   // wave-uniform: no boundary in this 8-edge group
            acc += (((f0 + f1) + (f2 + f3)) + ((f4 + f5) + (f6 + f7)));
        } else {
            float fv[8] = {f0, f1, f2, f3, f4, f5, f6, f7};
#pragma unroll
            for (int j = 0; j < 8; ++j) {
                if (gm & (1u << j)) {
                    pbuf[(size_t)curp * 64 + lane] = acc;
                    acc = 0.f;
                    curp = __shfl(pstv, g * 8 + j);
                }
                acc += fv[j];
            }
        }
    }
    pbuf[(size_t)curp * 64 + lane] = acc;
}

// fixup: agg[i] = sum of node i's partial rows (R10, verified); zero for deg-0 nodes
__global__ __launch_bounds__(256) void fixup_kernel(
        const float* __restrict__ pbuf, const int* __restrict__ off,
        const int* __restrict__ pstart, float* __restrict__ agg, int N) {
    int tid = blockIdx.x * blockDim.x + threadIdx.x;
    int i = tid >> 2, q = tid & 3;
    if (i >= N) return;
    int k0 = off[i], k1 = off[i + 1];
    float acc[16];
#pragma unroll
    for (int c = 0; c < 16; ++c) acc[c] = 0.f;
    if (k1 > k0) {
        int nsp = ((k1 - 1) >> 6) - (k0 >> 6) + 1;
        int p = pstart[i];
        for (int j = 0; j < nsp; ++j) {
            const float4* pr = (const float4*)(pbuf + (size_t)(p + j) * 64 + q * 16);
#pragma unroll
            for (int c = 0; c < 4; ++c) {
                float4 v = pr[c];
                acc[4 * c] += v.x; acc[4 * c + 1] += v.y;
                acc[4 * c + 2] += v.z; acc[4 * c + 3] += v.w;
            }
        }
    }
    float4* o4 = (float4*)(agg + (size_t)i * 64 + q * 16);
#pragma unroll
    for (int c = 0; c < 4; ++c)
        o4[c] = make_float4(acc[4 * c], acc[4 * c + 1], acc[4 * c + 2], acc[4 * c + 3]);
}

// ---------------- MFMA update: h = relu([h,agg] @ Wu + bu) + h (R10, verified) ----------------
__global__ __launch_bounds__(128) void update_mfma_kernel(
        const short* __restrict__ WuT, const float* __restrict__ bu,
        float* __restrict__ h, const float* __restrict__ agg, int N) {
    __shared__ short lds_w[64 * 136];
    __shared__ short lds_x[2][64 * 136];
    const int tid = threadIdx.x, wid = tid >> 6, lane = tid & 63;
    const int r = lane & 15, q = lane >> 4;
    const int nb0 = blockIdx.x * 128 + wid * 64;
#pragma unroll
    for (int j = 0; j < 8; ++j) {
        int f8 = (tid * 8 + j) * 8;
        int row = f8 >> 7, k = f8 & 127;
        *(uint4*)&lds_w[row * 136 + k] = ((const uint4*)WuT)[tid * 8 + j];
    }
    short* xt = &lds_x[wid][0];
#pragma unroll 1
    for (int it = 0; it < 32; ++it) {
        int f4 = it * 64 + lane;
        int node = f4 >> 5, c4 = f4 & 31;
        int gn = nb0 + node; if (gn >= N) gn = N - 1;
        const float4* src = (c4 < 16)
            ? ((const float4*)h + (size_t)gn * 16 + c4)
            : ((const float4*)agg + (size_t)gn * 16 + (c4 - 16));
        float4 v = *src;
        *(uint2*)&xt[node * 136 + c4 * 4] =
            make_uint2(pack2bf(v.x, v.y), pack2bf(v.z, v.w));
    }
    __syncthreads();
    bfrag bg[4][4];
#pragma unroll
    for (int ni = 0; ni < 4; ++ni)
#pragma unroll
        for (int ki = 0; ki < 4; ++ki)
            bg[ni][ki] = *(const bfrag*)&lds_w[(ni * 16 + r) * 136 + ki * 32 + q * 8];
    float buv[4];
#pragma unroll
    for (int ni = 0; ni < 4; ++ni) buv[ni] = bu[ni * 16 + r];
    ffrag C[4][4];
#pragma unroll
    for (int mi = 0; mi < 4; ++mi) {
        bfrag af[4];
#pragma unroll
        for (int ki = 0; ki < 4; ++ki)
            af[ki] = *(const bfrag*)&xt[(mi * 16 + r) * 136 + ki * 32 + q * 8];
#pragma unroll
        for (int ni = 0; ni < 4; ++ni) {
            ffrag c = {buv[ni], buv[ni], buv[ni], buv[ni]};
#pragma unroll
            for (int ki = 0; ki < 4; ++ki)
                c = __builtin_amdgcn_mfma_f32_16x16x32_bf16(af[ki], bg[ni][ki], c, 0, 0, 0);
            C[mi][ni] = c;
        }
    }
#pragma unroll
    for (int mi = 0; mi < 4; ++mi)
#pragma unroll
        for (int rr = 0; rr < 4; ++rr) {
            int nl = mi * 16 + q * 4 + rr;
            int gn = nb0 + nl;
            if (gn < N) {
#pragma unroll
                for (int ni = 0; ni < 4; ++ni) {
                    float hold = bf2f((unsigned short)xt[nl * 136 + ni * 16 + r]);
                    h[(size_t)gn * 64 + ni * 16 + r] =
                        fmaxf(C[mi][ni][rr], 0.f) + hold;
                }
            }
        }
}

// ---------------- fallback gather (tiny ws; R3 structure; bf16 A) ----------------
__global__ __launch_bounds__(256) void gather_msg_fallback(
        const float* __restrict__ Wm2, const float* __restrict__ We,
        const float* __restrict__ be, const void* __restrict__ ef,
        const int* __restrict__ srcs, const int* __restrict__ eid,
        const int* __restrict__ off, const unsigned short* __restrict__ Ab,
        float* __restrict__ agg, int N, const int* __restrict__ flagp) {
    int i = blockIdx.x * blockDim.x + threadIdx.x;
    if (i >= N) return;
    int isf32 = *flagp;
    int k0 = off[i], k1 = off[i + 1];
    float acc[64];
#pragma unroll
    for (int c = 0; c < 64; ++c) acc[c] = 0.f;
    for (int k = k0; k < k1; ++k) {
        int s = srcs[k];
        int e = eid[k];
        const uint4* a4 = (const uint4*)(Ab + (size_t)s * 64);
        float t[64];
#pragma unroll
        for (int c = 0; c < 8; ++c) {
            uint4 v = a4[c];
            t[8 * c]     = bflo(v.x); t[8 * c + 1] = bfhi(v.x);
            t[8 * c + 2] = bflo(v.y); t[8 * c + 3] = bfhi(v.y);
            t[8 * c + 4] = bflo(v.z); t[8 * c + 5] = bfhi(v.z);
            t[8 * c + 6] = bflo(v.w); t[8 * c + 7] = bfhi(v.w);
        }
        float efv[8];
        if (isf32) {
            const float4* e4 = (const float4*)ef + (size_t)e * 2;
            float4 ra = e4[0], rb = e4[1];
            efv[0]=ra.x; efv[1]=ra.y; efv[2]=ra.z; efv[3]=ra.w;
            efv[4]=rb.x; efv[5]=rb.y; efv[6]=rb.z; efv[7]=rb.w;
        } else {
            uint4 rr = ((const uint4*)ef)[e];
            efv[0]=bflo(rr.x); efv[1]=bfhi(rr.x); efv[2]=bflo(rr.y); efv[3]=bfhi(rr.y);
            efv[4]=bflo(rr.z); efv[5]=bfhi(rr.z); efv[6]=bflo(rr.w); efv[7]=bfhi(rr.w);
        }
#pragma unroll 1
        for (int d0 = 0; d0 < 64; d0 += 8) {
            float ev[8];
#pragma unroll
            for (int dd = 0; dd < 8; ++dd) {
                float a = be[d0 + dd];
#pragma unroll
                for (int kk = 0; kk < 8; ++kk) a = fmaf(efv[kk], We[kk * 64 + d0 + dd], a);
                ev[dd] = fmaxf(a, 0.f);
            }
#pragma unroll
            for (int dd = 0; dd < 8; ++dd) {
                const float* w = Wm2 + (d0 + dd) * 64;
#pragma unroll
                for (int c = 0; c < 64; ++c) t[c] = fmaf(ev[dd], w[c], t[c]);
            }
        }
#pragma unroll
        for (int c = 0; c < 64; ++c) acc[c] += fmaxf(t[c], 0.f);
    }
    float4* o4 = (float4*)(agg + (size_t)i * 64);
#pragma unroll
    for (int c = 0; c < 16; ++c)
        o4[c] = make_float4(acc[4 * c], acc[4 * c + 1], acc[4 * c + 2], acc[4 * c + 3]);
}

// ---------------- MFMA scores: out[p] = relu([h_s|h_d]@Ws1+bs1) . Ws2 + bs2 ----------------
__global__ __launch_bounds__(128) void scores_mfma_kernel(
        const short* __restrict__ Ws1T, const float* __restrict__ bs1,
        const float* __restrict__ Ws2, const float* __restrict__ bs2,
        const int* __restrict__ ods, const int* __restrict__ odd,
        const float* __restrict__ h, void* __restrict__ out, int P,
        const int* __restrict__ flagp) {
    __shared__ short lds_w[64 * 136];
    __shared__ short lds_x[2][64 * 136];
    const int tid = threadIdx.x, wid = tid >> 6, lane = tid & 63;
    const int r = lane & 15, q = lane >> 4;
    const int pb0 = blockIdx.x * 128 + wid * 64;
#pragma unroll
    for (int j = 0; j < 8; ++j) {
        int f8 = (tid * 8 + j) * 8;
        int row = f8 >> 7, k = f8 & 127;
        *(uint4*)&lds_w[row * 136 + k] = ((const uint4*)Ws1T)[tid * 8 + j];
    }
    short* xt = &lds_x[wid][0];
#pragma unroll 1
    for (int it = 0; it < 32; ++it) {
        int f4 = it * 64 + lane;
        int pr = f4 >> 5, c4 = f4 & 31;
        int gp = pb0 + pr; if (gp >= P) gp = P - 1;
        int node = (c4 < 16) ? ods[gp] : odd[gp];
        int cc = (c4 < 16) ? c4 : (c4 - 16);
        float4 v = ((const float4*)h)[(size_t)node * 16 + cc];
        *(uint2*)&xt[pr * 136 + c4 * 4] =
            make_uint2(pack2bf(v.x, v.y), pack2bf(v.z, v.w));
    }
    __syncthreads();

    bfrag bg[4][4];
#pragma unroll
    for (int ni = 0; ni < 4; ++ni)
#pragma unroll
        for (int ki = 0; ki < 4; ++ki)
            bg[ni][ki] = *(const bfrag*)&lds_w[(ni * 16 + r) * 136 + ki * 32 + q * 8];
    float buv[4], w2v[4];
#pragma unroll
    for (int ni = 0; ni < 4; ++ni) { buv[ni] = bs1[ni * 16 + r]; w2v[ni] = Ws2[ni * 16 + r]; }
    int isf32 = *flagp;
    float b2 = bs2[0];

#pragma unroll
    for (int mi = 0; mi < 4; ++mi) {
        bfrag af[4];
#pragma unroll
        for (int ki = 0; ki < 4; ++ki)
            af[ki] = *(const bfrag*)&xt[(mi * 16 + r) * 136 + ki * 32 + q * 8];
        float part[4] = {0.f, 0.f, 0.f, 0.f};
#pragma unroll
        for (int ni = 0; ni < 4; ++ni) {
            ffrag c = {buv[ni], buv[ni], buv[ni], buv[ni]};
#pragma unroll
            for (int ki = 0; ki < 4; ++ki)
                c = __builtin_amdgcn_mfma_f32_16x16x32_bf16(af[ki], bg[ni][ki], c, 0, 0, 0);
#pragma unroll
            for (int rr = 0; rr < 4; ++rr)
                part[rr] = fmaf(fmaxf(c[rr], 0.f), w2v[ni], part[rr]);
        }
#pragma unroll
        for (int rr = 0; rr < 4; ++rr) {
            float v = part[rr];
            v += __shfl_xor(v, 1); v += __shfl_xor(v, 2);
            v += __shfl_xor(v, 4); v += __shfl_xor(v, 8);
            if (r == 0) {
                int p = pb0 + mi * 16 + q * 4 + rr;
                if (p < P) {
                    float score = v + b2;
                    if (isf32) ((float*)out)[p] = score;
                    else ((__hip_bfloat16*)out)[p] = __float2bfloat16(score);
                }
            }
        }
    }
}

// ---------------- graph embed ----------------
__global__ __launch_bounds__(256) void embed_kernel(
        const float* __restrict__ h, float* __restrict__ gsum, int N) {
    __shared__ float red[256];
    int c = threadIdx.x & 63;
    int sub = threadIdx.x >> 6;   // 0..3
    float a = 0.f;
    for (int i = blockIdx.x * 4 + sub; i < N; i += gridDim.x * 4)
        a += h[(size_t)i * 64 + c];
    red[threadIdx.x] = a;
    __syncthreads();
    if (threadIdx.x < 64) {
        float t = red[threadIdx.x] + red[threadIdx.x + 64] +
                  red[threadIdx.x + 128] + red[threadIdx.x + 192];
        unsafeAtomicAdd(&gsum[threadIdx.x], t);
    }
}

// ---------------- dynamic-K head (wave-parallel; R14 verified) ----------------
__global__ void khead_kernel(const float* __restrict__ ws,
                             void* __restrict__ out, int N, int P,
                             const int* __restrict__ flagp) {
    __shared__ float sh1[32];
    __shared__ float sh2[16];
    int lane = threadIdx.x;   // 64 threads, 1 wave
    float invN = 1.f / (float)N;
    float a1 = (lane < 32) ? ws[OFF_BK1 + lane] : 0.f;
#pragma unroll
    for (int i = 0; i < 68; ++i) {
        float xi = (i < 64) ? ws[OFF_GSUM + i] * invN : ws[OFF_TS + i - 64];
        if (lane < 32) a1 = fmaf(xi, ws[OFF_WK1 + i * 32 + lane], a1);
    }
    if (lane < 32) sh1[lane] = fmaxf(a1, 0.f);
    __syncthreads();
    float a2 = (lane < 16) ? ws[OFF_BK2 + lane] : 0.f;
#pragma unroll
    for (int j = 0; j < 32; ++j) {
        if (lane < 16) a2 = fmaf(sh1[j], ws[OFF_WK2 + j * 16 + lane], a2);
    }
    if (lane < 16) sh2[lane] = fmaxf(a2, 0.f);
    __syncthreads();
    if (lane == 0) {
        float raw = ws[OFF_BK3];
#pragma unroll
        for (int k2 = 0; k2 < 16; ++k2) raw = fmaf(sh2[k2], ws[OFF_WK3 + k2], raw);
        float sig = 1.f / (1.f + expf(-raw));
        float k = 1.f + 49.f * sig;
        if (*flagp) ((float*)out)[P] = k;
        else ((__hip_bfloat16*)out)[P] = __float2bfloat16(k);
    }
}

extern "C" void kernel_launch(void* const* d_in, const int* in_sizes, int n_in,
                              void* d_out, int out_size, void* d_ws, size_t ws_size,
                              hipStream_t stream) {
    const void* nf = d_in[0];
    const int*  ei = (const int*)d_in[1];
    const void* ef = d_in[2];
    const int*  od = (const int*)d_in[3];
    float* ws = (float*)d_ws;

    const int N = in_sizes[0] / 16;   // 50000
    const int E = in_sizes[1] / 2;    // 1200000
    const int P = in_sizes[3] / 2;    // 10000

    // layout: h, agg, A(bf16); deg/spans, off, cursor, pstart, eid, srcs, Wtrans, rank; rec; pbuf
    float* h      = ws + OFF_H;
    float* agg    = h + (size_t)N * 64;
    unsigned short* Ab = (unsigned short*)(agg + (size_t)N * 64);  // N*64 bf16 (half the f32 slot)
    int*   deg    = (int*)(agg + (size_t)N * 64 + (size_t)N * 32); // N (reused as spans)
    int*   off    = deg + N;                      // N+1
    int*   cursor = off + N + 1;                  // N
    int*   pstart = cursor + N;                   // N+1
    int*   eid    = pstart + N + 1;               // E (fallback only)
    int*   srcs   = eid + E;                      // E (fallback only)
    short* WbT    = (short*)(srcs + E);           // 59392 shorts: WbT|W1T|WuT|WeT|Ws1T
    short* W1T    = WbT + 12288;
    short* WuT    = WbT + 24576;
    short* WeT    = WbT + 49152;
    short* Ws1T   = WbT + 51200;
    int*   rank   = (int*)(WbT + 59392);          // E (big path only)
    int*   flag   = (int*)(ws + OFF_FLAG);
    int*   bsum   = (int*)(ws + OFF_BSUM);
    int*   boff   = (int*)(ws + OFF_BOFF);

    size_t fsofar = (size_t)OFF_H + 2 * (size_t)N * 64 + (size_t)N * 32
                  + (size_t)(N + (N + 1) + N + (N + 1) + E + E + E) + 29696;
    size_t recOff = (fsofar + 7) & ~(size_t)7;            // record base align
    float* rec = ws + recOff;
    size_t pbufOff = recOff + (size_t)E * 6;
    float* pbuf = ws + pbufOff;
    long pbufRows = (long)N + E / 64 + 128;
    size_t needBytes = (pbufOff + (size_t)pbufRows * 64) * sizeof(float);
    const bool big = (ws_size >= needBytes);

    const int* srcv = ei;
    const int* dstv = ei + E;

    // 0. dtype detect
    detect_dtype_kernel<<<1, 64, 0, stream>>>((const unsigned short*)nf, flag);

    // 1. convert weights to f32 in ws; build transposed bf16 weights
    ConvArgs ca;
    const int srcidx[19] = {5, 6, 7, 8, 9, 10, 11, 12, 13, 14, 15, 16, 17, 18, 19, 20, 21, 22, 4};
    const int wsoff[19]  = {OFF_WN, OFF_BN, OFF_WE, OFF_BE, OFF_WM, OFF_BM, OFF_WU, OFF_BU,
                            OFF_WS1, OFF_BS1, OFF_WS2, OFF_BS2, OFF_WK1, OFF_BK1, OFF_WK2,
                            OFF_BK2, OFF_WK3, OFF_BK3, OFF_TS};
    int maxn = 0;
    for (int i = 0; i < 19; ++i) {
        ca.src[i] = d_in[srcidx[i]];
        ca.off[i] = wsoff[i];
        ca.n[i]   = in_sizes[srcidx[i]];
        if (ca.n[i] > maxn) maxn = ca.n[i];
    }
    dim3 cgrid((maxn + 255) / 256, 19);
    convert_all_kernel<<<cgrid, 256, 0, stream>>>(ca, ws, flag);
    wtrans_prep_kernel<<<232, 256, 0, stream>>>(ws, WbT);

    // 2. node projection
    node_proj_kernel<<<(N * 64 + 255) / 256, 256, 0, stream>>>(nf, ws, h, N, flag);

    // 3. build CSR by dst (once). count records per-edge rank so fill
    //    needs no atomics in big mode.
    hipMemsetAsync(deg, 0, (size_t)N * sizeof(int), stream);
    count_kernel<<<(E + 255) / 256, 256, 0, stream>>>(dstv, deg, rank, E, big ? 1 : 0);
    int nb = (N + 255) / 256;
    scan_blocks_kernel<<<nb, 256, 0, stream>>>(deg, cursor, bsum, N);
    scan_bsum_kernel<<<1, 256, 0, stream>>>(bsum, boff, nb);
    scan_finalize_kernel<<<nb, 256, 0, stream>>>(deg, cursor, boff, off, cursor, N, E);
    fill_kernel<<<(E + 255) / 256, 256, 0, stream>>>(
        srcv, dstv, ef, cursor, rank, off, eid, srcs, rec, E, big ? 1 : 0, flag);

    // 3b. pstart = exclusive scan of wave-span counts (big path only)
    if (big) {
        spans_kernel<<<nb, 256, 0, stream>>>(off, deg, N);       // deg := spans
        scan_blocks_kernel<<<nb, 256, 0, stream>>>(deg, cursor, bsum, N);
        scan_bsum_kernel<<<1, 256, 0, stream>>>(bsum, boff, nb);
        scan_finalize_kernel<<<nb, 256, 0, stream>>>(deg, cursor, boff, pstart, cursor, N, 0);
    }

    // 4. GNN layers (R19 structure: nodeA -> msg -> fixup -> update)
    const int N4 = N * 4;
    const int mblocks = (E + 255) / 256;
    const int ablocks = (N + 255) / 256;
    const int ublocks = (N + 127) / 128;
    for (int l = 0; l < 3; ++l) {
        nodeA_mfma_kernel<<<ablocks, 256, 0, stream>>>(
            W1T + l * 4096, ws + OFF_BM + l * 64, h, Ab, N);
        if (big) {
            msg_mfma_red<<<mblocks, 256, 0, stream>>>(
                WeT, ws + OFF_BE, WbT + l * 4096, rec, Ab, pbuf, off, pstart, E);
            fixup_kernel<<<(N4 + 255) / 256, 256, 0, stream>>>(
                pbuf, off, pstart, agg, N);
        } else {
            const float* Wm2 = ws + OFF_WM + l * 8192 + 4096;
            gather_msg_fallback<<<(N + 255) / 256, 256, 0, stream>>>(
                Wm2, ws + OFF_WE, ws + OFF_BE, ef, srcs, eid, off, Ab, agg, N, flag);
        }
        update_mfma_kernel<<<ublocks, 128, 0, stream>>>(
            WuT + l * 8192, ws + OFF_BU + l * 64, h, agg, N);
    }

    // 5. per-flow scores (MFMA)
    scores_mfma_kernel<<<(P + 127) / 128, 128, 0, stream>>>(
        Ws1T, ws + OFF_BS1, ws + OFF_WS2, ws + OFF_BS2,
        od, od + P, h, d_out, P, flag);

    // 6. graph embedding + dynamic-K head
    hipMemsetAsync(ws + OFF_GSUM, 0, 64 * sizeof(float), stream);
    embed_kernel<<<256, 256, 0, stream>>>(h, ws + OFF_GSUM, N);
    khead_kernel<<<1, 64, 0, stream>>>(ws, d_out, N, P, flag);
}